// Round 13
// baseline (433.305 us; speedup 1.0000x reference)
//
#include <hip/hip_runtime.h>
#include <hip/hip_bf16.h>
#include <math.h>

typedef __hip_bfloat16 bf16;
typedef __attribute__((ext_vector_type(8))) short short8;
typedef __attribute__((ext_vector_type(4))) float f32x4;

#define FB 513
#define HD 1026
#define NN 1024
#define MR 4096      // 32*128 rows
#define NE 8
#define BATCH 32

#define XINT_LD 1280   // 2*FB padded to 5*256 (DFT gemm8p N)
#define BIAS_LD 1056
#define FINV_LD 1088   // 17*64 (Finv / B2t K-stride)
#define HP_LD   2080   // per-expert window in H'
#define B1_ROWS 2176
#define KCAT    16640  // 8*2080
#define MAG_LD  520
#define FF_ROWS 1280

__device__ __forceinline__ void gload16(const void* g, void* l) {
    __builtin_amdgcn_global_load_lds((const __attribute__((address_space(1))) void*)g,
                                     (__attribute__((address_space(3))) void*)l, 16, 0, 0);
}
__device__ __forceinline__ bf16 f2b(float v) { return __float2bfloat16(v); }
__device__ __forceinline__ unsigned short f2bu(float v) {
    bf16 b = __float2bfloat16(v);
    return *reinterpret_cast<unsigned short*>(&b);
}
__device__ __forceinline__ float bu2f(unsigned short u) {
    return __uint_as_float(((unsigned)u) << 16);
}
__device__ __forceinline__ unsigned pack2(float a, float b) {
    return (unsigned)f2bu(a) | ((unsigned)f2bu(b) << 16);
}

// XCD-aware bijective remap for the 128^2 kernel (grid.x*grid.y % 8 == 0)
__device__ __forceinline__ void xcd_swizzle(int* px, int* py) {
    int gx = gridDim.x;
    int orig = blockIdx.x + gx * blockIdx.y;
    int q = (gx * gridDim.y) >> 3;
    int wg = (orig & 7) * q + (orig >> 3);
    *px = wg % gx;
    *py = wg / gx;
}

// ---------------------------------------------------------------------------
__global__ void prep_kernel(const float* __restrict__ bp, int* __restrict__ se) {
    if (threadIdx.x == 0 && blockIdx.x == 0) {
        float b[9];
        b[0] = 0.0f; b[8] = 1.0f;
        for (int i = 0; i < 7; i++) b[i + 1] = 1.0f / (1.0f + expf(-bp[i]));
        for (int i = 1; i < 9; i++) { float v = b[i]; int j = i - 1;
            while (j >= 0 && b[j] > v) { b[j + 1] = b[j]; j--; } b[j + 1] = v; }
        int idx[9];
        for (int i = 0; i < 9; i++) idx[i] = (int)(b[i] * (float)(FB - 1));
        for (int e = 0; e < NE; e++) {
            se[2 * e] = idx[e];
            se[2 * e + 1] = (e < NE - 1) ? idx[e + 1] : FB;
        }
    }
}

// ---------------------------------------------------------------------------
// prep_all: blocks [0, NB_BULK) elementwise [Ffwd | Finv | B1 | X];
//           blocks [NB_BULK, +1224) = LDS-tiled B2t transpose.
// ---------------------------------------------------------------------------
#define N_FF  ((long)FF_ROWS * NN)                // 1,310,720
#define N_FI  (1024L * FINV_LD)                   // 1,114,112
#define N_B1P ((long)NE * B1_ROWS * (XINT_LD / 2))// 11,141,120
#define N_XP  ((long)MR * NN / 2)                 // 2,097,152
#define N_PREP (N_FF + N_FI + N_B1P + N_XP)       // 15,663,104 = 61184*256
#define NB_BULK 61184
#define NB_B2T  1224                              // 9*17*8

__global__ void prep_all(const float* __restrict__ W1r, const float* __restrict__ W1i,
                         const float* __restrict__ W2r, const float* __restrict__ W2i,
                         const float* __restrict__ X, const int* __restrict__ se,
                         bf16* __restrict__ Ffwd, bf16* __restrict__ Finv,
                         bf16* __restrict__ B1, bf16* __restrict__ B2t,
                         bf16* __restrict__ Xb) {
    __shared__ float sR[64][65], sI[64][65];
    int tid = threadIdx.x;
    if (blockIdx.x >= NB_BULK) {
        // ---- B2t transpose path
        int bid2 = blockIdx.x - NB_BULK;
        int fx = bid2 % 9;
        int hy = (bid2 / 9) % 17;
        int e = bid2 / 153;
        int f0 = fx * 64, h0 = hy * 64;
#pragma unroll
        for (int rep = 0; rep < 16; rep++) {
            int idx = tid + rep * 256;
            int fl = idx >> 6, hl = idx & 63;
            int f = f0 + fl, h = h0 + hl;
            bool ok = (f < FB) && (h < HD);
            size_t wi = ((size_t)e * FB + f) * HD + h;
            sR[fl][hl] = ok ? W2r[wi] : 0.0f;
            sI[fl][hl] = ok ? W2i[wi] : 0.0f;
        }
        __syncthreads();
#pragma unroll
        for (int rep = 0; rep < 4; rep++) {
            int idx = tid + rep * 256;
            int hl = idx >> 4, ch = idx & 15;
            int h = h0 + hl;
            int c0 = 2 * f0 + ch * 8;
            if (c0 >= FINV_LD) continue;
            short8 lo, hi;
#pragma unroll
            for (int j = 0; j < 4; j++) {
                int fl = ch * 4 + j;
                float wr = sR[fl][hl], wim = sI[fl][hl];
                lo[2 * j]     = (short)f2bu(wr);
                lo[2 * j + 1] = (short)f2bu(wim);
                hi[2 * j]     = (short)f2bu(-wim);
                hi[2 * j + 1] = (short)f2bu(wr);
            }
            if (h < HD) {
                *(short8*)(B2t + ((size_t)e * HP_LD + h) * FINV_LD + c0) = lo;
                *(short8*)(B2t + ((size_t)e * HP_LD + HD + h) * FINV_LD + c0) = hi;
            } else if (HD + h < HP_LD) {
                short8 z = {};
                *(short8*)(B2t + ((size_t)e * HP_LD + HD + h) * FINV_LD + c0) = z;
            }
        }
        return;
    }
    long i = (long)blockIdx.x * 256 + tid;
    const float TWO_PI = 6.283185307179586f;
    if (i < N_FF) {                 // Ffwd: rows 2f=cos, 2f+1=-sin; rows>=1026 zero
        int n = (int)(i >> 10), t = (int)(i & (NN - 1));
        float v = 0.0f;
        if (n < 2 * FB) {
            int f = n >> 1, k = (f * t) & (NN - 1);
            float s, c; sincosf(TWO_PI * (float)k / (float)NN, &s, &c);
            v = (n & 1) ? -s : c;
        }
        Ffwd[i] = f2b(v);
        return;
    }
    i -= N_FF;
    if (i < N_FI) {                 // Finv[1024][1088]
        int t = (int)(i / FINV_LD), k = (int)(i % FINV_LD);
        float v = 0.0f;
        if (k < 2 * FB) {
            int f = k >> 1, kk = (f * t) & (NN - 1);
            float s, c; sincosf(TWO_PI * (float)kk / (float)NN, &s, &c);
            float cf = (f == 0 || f == FB - 1) ? 1.0f : 2.0f;
            float sc = cf * (1.0f / (float)NN);
            v = (k & 1) ? -s * sc : c * sc;
        }
        Finv[i] = f2b(v);
        return;
    }
    i -= N_FI;
    if (i < N_B1P) {                // B1[e][2176][1280], pair (2f,2f+1)/thread
        int f = (int)(i % (XINT_LD / 2));
        long t = i / (XINT_LD / 2);
        int n = (int)(t % B1_ROWS);
        int e = (int)(t / B1_ROWS);
        float ve = 0.0f, vo = 0.0f;
        if (n < 2 * HD && f < FB && f >= se[2 * e] && f < se[2 * e + 1]) {
            int hi_part = (n >= HD);
            int h = hi_part ? n - HD : n;
            long wi = ((long)e * HD + h) * FB + f;
            float wr = W1r[wi], wim = W1i[wi];
            ve = hi_part ? wim : wr;
            vo = hi_part ? wr : -wim;
        }
        *(unsigned*)(B1 + ((size_t)(e * B1_ROWS + n)) * XINT_LD + 2 * f) = pack2(ve, vo);
        return;
    }
    i -= N_B1P;
    if (i < N_XP) {                 // X fp32 -> bf16, paired
        float2 v = ((const float2*)X)[i];
        *(unsigned*)(Xb + 2 * i) = pack2(v.x, v.y);
    }
}

// ---------------------------------------------------------------------------
__global__ void mag_kernel(const bf16* __restrict__ Xint, float* __restrict__ magp) {
    int b = blockIdx.x, g = blockIdx.y, t = threadIdx.x;
    float acc[3] = {0.0f, 0.0f, 0.0f};
    const bf16* base = Xint + ((size_t)b * 128 + g * 16) * XINT_LD;
    for (int c = 0; c < 16; c++) {
        const bf16* row = base + (size_t)c * XINT_LD;
#pragma unroll
        for (int kk = 0; kk < 3; kk++) {
            int f = t + 256 * kk;
            if (f < FB) {
                float xr = __bfloat162float(row[2 * f]);
                float xi = __bfloat162float(row[2 * f + 1]);
                acc[kk] += sqrtf(xr * xr + xi * xi);
            }
        }
    }
#pragma unroll
    for (int kk = 0; kk < 3; kk++) {
        int f = t + 256 * kk;
        if (f < FB) magp[((size_t)b * 8 + g) * MAG_LD + f] = acc[kk];
    }
}

// ---------------------------------------------------------------------------
// gate + scaled gated-bias: biasCs[b][c] = (c_f/N)*sum_e g_e*b2[e][f]
// ---------------------------------------------------------------------------
__global__ void gate_bias_kernel(const float* __restrict__ magp, const float* __restrict__ gW,
                                 const float* __restrict__ gb, const float* __restrict__ b2r,
                                 const float* __restrict__ b2i, float* __restrict__ gate,
                                 float* __restrict__ biasCs) {
    __shared__ float sred[256];
    __shared__ float sg[8];
    int b = blockIdx.x, tid = threadIdx.x;
    int e = tid & 7, j = tid >> 3;
    float acc = 0.0f;
    for (int f = j; f < FB; f += 32) {
        float m = 0.0f;
#pragma unroll
        for (int g = 0; g < 8; g++) m += magp[((size_t)b * 8 + g) * MAG_LD + f];
        acc += m * (1.0f / 128.0f) * gW[e * FB + f];
    }
    sred[tid] = acc;
    __syncthreads();
    if (tid < 64) {
        float a = sred[tid] + sred[tid + 64] + sred[tid + 128] + sred[tid + 192];
        a += __shfl_xor(a, 8); a += __shfl_xor(a, 16); a += __shfl_xor(a, 32);
        float logit = a + gb[e];
        float mx = logit;
        mx = fmaxf(mx, __shfl_xor(mx, 1)); mx = fmaxf(mx, __shfl_xor(mx, 2)); mx = fmaxf(mx, __shfl_xor(mx, 4));
        float ex = expf(logit - mx);
        float sum = ex;
        sum += __shfl_xor(sum, 1); sum += __shfl_xor(sum, 2); sum += __shfl_xor(sum, 4);
        if (tid < 8) { float g_ = ex / sum; sg[tid] = g_; gate[b * NE + tid] = g_; }
    }
    __syncthreads();
    for (int c = tid; c < BIAS_LD; c += 256) {
        float v = 0.0f;
        if (c < 2 * FB) {
            int f = c >> 1;
            const float* bb = (c & 1) ? b2i : b2r;
#pragma unroll
            for (int ee = 0; ee < NE; ee++) v += sg[ee] * bb[ee * FB + f];
            float cf = (f == 0 || f == FB - 1) ? 1.0f : 2.0f;
            v *= cf * (1.0f / (float)NN);
        }
        biasCs[b * BIAS_LD + c] = v;
    }
}

// ---------------------------------------------------------------------------
// biasT[b][t] = sum_c biasCs[b][c]*Ffwd[c][t]. Grid (16, BATCH), 512 blocks.
// 64 t per block; 4-way c-split per thread group + LDS reduce (deterministic).
// ---------------------------------------------------------------------------
__global__ void biasT_kernel(const float* __restrict__ biasCs, const bf16* __restrict__ Ffwd,
                             float* __restrict__ biasT) {
    __shared__ float red[256];
    int b = blockIdx.y;
    int t = blockIdx.x * 64 + (threadIdx.x & 63);
    int part = threadIdx.x >> 6;       // 0..3
    float s = 0.0f;
    for (int c = part; c < 2 * FB; c += 4)
        s += biasCs[b * BIAS_LD + c] * __bfloat162float(Ffwd[(size_t)c * NN + t]);
    red[threadIdx.x] = s;
    __syncthreads();
    if (threadIdx.x < 64) {
        float v = red[threadIdx.x] + red[threadIdx.x + 64] +
                  red[threadIdx.x + 128] + red[threadIdx.x + 192];
        biasT[b * NN + t] = v;
    }
}

// ---------------------------------------------------------------------------
// out[r][t] = sum_z bf16plane_z[r][t] + biasT[r>>7][t]
// ---------------------------------------------------------------------------
__global__ void reduce_out4(const bf16* __restrict__ planes, const float* __restrict__ biasT,
                            float* __restrict__ out) {
    long idx = (long)blockIdx.x * 256 + threadIdx.x;
    if (idx >= (long)MR * NN / 8) return;
    size_t base = (size_t)idx * 8;
    long r = base >> 10;
    int t = (int)(base & (NN - 1));
    float s[8] = {};
#pragma unroll
    for (int z = 0; z < 4; z++) {
        short8 v = *(const short8*)(planes + (size_t)z * MR * NN + base);
#pragma unroll
        for (int j = 0; j < 8; j++) s[j] += bu2f((unsigned short)v[j]);
    }
    const float* bT = biasT + (r >> 7) * NN + t;
    float4 o0 = {s[0] + bT[0], s[1] + bT[1], s[2] + bT[2], s[3] + bT[3]};
    float4 o1 = {s[4] + bT[4], s[5] + bT[5], s[6] + bT[6], s[7] + bT[7]};
    *(float4*)(out + base) = o0;
    *(float4*)(out + base + 4) = o1;
}

// ---------------------------------------------------------------------------
// 128^2 MFMA GEMM (L1 only): EPI1 = relu(acc+bias)*gate -> bf16, per-z expert
// ---------------------------------------------------------------------------
template <int EPI>
__global__ void gemm_mfma(const bf16* __restrict__ A, int lda,
                          const bf16* __restrict__ B, int ldb, size_t zBstride,
                          void* __restrict__ Cv, int ldc, size_t zCoff,
                          int N, int K, int kPerZ,
                          const int* __restrict__ se2,
                          const float* __restrict__ biasR, const float* __restrict__ biasI,
                          int zBias, const float* __restrict__ gate8) {
    __shared__ bf16 As[128 * 32];
    __shared__ bf16 Bs[128 * 32];
    int tid = threadIdx.x;
    int zz = blockIdx.z;
    int bx, by;
    xcd_swizzle(&bx, &by);
    int row0 = by * 128, col0 = bx * 128;
    const bf16* Bz = B + (size_t)zz * zBstride;

    int kS, kE;
    if (EPI == 1) { int s = se2[2 * zz], e = se2[2 * zz + 1]; kS = (2 * s) & ~31; kE = (2 * e + 31) & ~31; }
    else          { kS = zz * kPerZ; kE = min(K, kS + kPerZ); }

    f32x4 acc[4][4] = {};

    int lane = tid & 63, wid = tid >> 6;
    int wrB = (wid >> 1) << 6, wcB = (wid & 1) << 6;
    int lr = lane & 15, lk = (lane >> 4) << 3;

    int r_a = tid >> 2, c_a = (tid & 3) << 3;
    int r_b = (tid + 256) >> 2, c_b = ((tid + 256) & 3) << 3;

    for (int kt = kS; kt < kE; kt += 32) {
        gload16(A + (size_t)(row0 + r_a) * lda + kt + c_a, &As[(size_t)tid * 8]);
        gload16(A + (size_t)(row0 + r_b) * lda + kt + c_b, &As[((size_t)tid + 256) * 8]);
        gload16(Bz + (size_t)(col0 + r_a) * ldb + kt + c_a, &Bs[(size_t)tid * 8]);
        gload16(Bz + (size_t)(col0 + r_b) * ldb + kt + c_b, &Bs[((size_t)tid + 256) * 8]);
        __syncthreads();
        short8 av[4], bv[4];
#pragma unroll
        for (int m = 0; m < 4; m++)
            av[m] = *(const short8*)&As[(wrB + m * 16 + lr) * 32 + lk];
#pragma unroll
        for (int n = 0; n < 4; n++)
            bv[n] = *(const short8*)&Bs[(wcB + n * 16 + lr) * 32 + lk];
#pragma unroll
        for (int m = 0; m < 4; m++)
#pragma unroll
            for (int n = 0; n < 4; n++)
                acc[m][n] = __builtin_amdgcn_mfma_f32_16x16x32_bf16(av[m], bv[n], acc[m][n], 0, 0, 0);
        __syncthreads();
    }

    int r0 = row0 + wrB + ((lane >> 4) << 2);
    int c0i = col0 + wcB + (lane & 15);
    float g = (EPI == 1) ? gate8[(row0 >> 7) * NE + zz] : 0.0f;

#pragma unroll
    for (int m = 0; m < 4; m++)
#pragma unroll
        for (int n = 0; n < 4; n++) {
            int c = c0i + n * 16;
            if (c >= N) continue;
#pragma unroll
            for (int j = 0; j < 4; j++) {
                int r = r0 + m * 16 + j;
                float v = acc[m][n][j];
                if (EPI == 1) {
                    v += (c < HD) ? biasR[zz * zBias + c] : biasI[zz * zBias + c - HD];
                    v = fmaxf(v, 0.0f) * g;
                    ((bf16*)Cv + (size_t)zz * zCoff)[(size_t)r * ldc + c] = f2b(v);
                } else {
                    ((float*)Cv + (size_t)zz * zCoff)[(size_t)r * ldc + c] = v;
                }
            }
        }
}

// ---------------------------------------------------------------------------
// 8-phase 256x256 GEMM body — 16x16x32 MFMA (R10-proven, 0 bank conflicts).
// R13: full-tile prefetch at iteration top (A+B = 8 gload16) with counted
// vmcnt(8) — both operands get a full K-tile of HBM-latency lead.
// ---------------------------------------------------------------------------
__device__ __forceinline__ void stage_half(const bf16* gbase, int ld, int kt,
                                           bf16* ldsBase, int tid) {
#pragma unroll
    for (int j = 0; j < 2; j++) {
        int r = j * 64 + (tid >> 3);
        int sc = ((tid & 7) ^ ((tid >> 3) & 7)) * 8;
        gload16(gbase + (size_t)r * ld + kt + sc, ldsBase + j * 4096 + tid * 8);
    }
}

#define MF(a, b, c) __builtin_amdgcn_mfma_f32_16x16x32_bf16(a, b, c, 0, 0, 0)
#define RD(off) (*(const short8*)(bc + (off)))
#define LOADA(dst, FM)                                                        \
    dst[0] = RD(aBase + (FM) * 1024 + cb0);                                   \
    dst[1] = RD(aBase + (FM) * 1024 + cb1);                                   \
    dst[2] = RD(aBase + (FM + 1) * 1024 + cb0);                               \
    dst[3] = RD(aBase + (FM + 1) * 1024 + cb1);
#define CLUST(FM, av)                                                         \
    __builtin_amdgcn_s_setprio(1);                                            \
    acc[FM][0] = MF(av[0], b0[0], acc[FM][0]);                                \
    acc[FM][0] = MF(av[1], b1[0], acc[FM][0]);                                \
    acc[FM][1] = MF(av[0], b0[1], acc[FM][1]);                                \
    acc[FM][1] = MF(av[1], b1[1], acc[FM][1]);                                \
    acc[FM][2] = MF(av[0], b0[2], acc[FM][2]);                                \
    acc[FM][2] = MF(av[1], b1[2], acc[FM][2]);                                \
    acc[FM][3] = MF(av[0], b0[3], acc[FM][3]);                                \
    acc[FM][3] = MF(av[1], b1[3], acc[FM][3]);                                \
    acc[FM + 1][0] = MF(av[2], b0[0], acc[FM + 1][0]);                        \
    acc[FM + 1][0] = MF(av[3], b1[0], acc[FM + 1][0]);                        \
    acc[FM + 1][1] = MF(av[2], b0[1], acc[FM + 1][1]);                        \
    acc[FM + 1][1] = MF(av[3], b1[1], acc[FM + 1][1]);                        \
    acc[FM + 1][2] = MF(av[2], b0[2], acc[FM + 1][2]);                        \
    acc[FM + 1][2] = MF(av[3], b1[2], acc[FM + 1][2]);                        \
    acc[FM + 1][3] = MF(av[2], b0[3], acc[FM + 1][3]);                        \
    acc[FM + 1][3] = MF(av[3], b1[3], acc[FM + 1][3]);                        \
    __builtin_amdgcn_s_setprio(0);
#define PBAR { __builtin_amdgcn_sched_barrier(0); __builtin_amdgcn_s_barrier(); }

__device__ __forceinline__ void gemm8p_body(
        bf16* sm, const bf16* __restrict__ A, int lda,
        const bf16* __restrict__ B, int ldb,
        bf16* __restrict__ C, int ldc,
        int row0, int col0, int kS, int nt) {
    int tid = threadIdx.x;
    const bf16* Ab = A + (size_t)row0 * lda;
    const bf16* Bb = B + (size_t)col0 * ldb;

    // prologue: stage tile 0 into buf0 (8 gload16 per thread-pair pattern)
    stage_half(Ab, lda, kS, sm, tid);
    stage_half(Ab + (size_t)128 * lda, lda, kS, sm + 8192, tid);
    stage_half(Bb, ldb, kS, sm + 16384, tid);
    stage_half(Bb + (size_t)128 * ldb, ldb, kS, sm + 24576, tid);

    f32x4 acc[8][4] = {};

    int l = tid & 63, w = tid >> 6;
    int wm = w >> 2, wn = w & 3;
    int lr = l & 15, lk4 = l >> 4;
    int swz = lr & 7;
    int cb0 = ((lk4) ^ swz) * 8;
    int cb1 = ((4 + lk4) ^ swz) * 8;
    int aBase = wm * 8192 + lr * 64;
    int bBase = 16384 + (wn >> 1) * 8192 + (wn & 1) * 4096 + lr * 64;

    for (int t = 0; t < nt; ++t) {
        const bf16* bc = sm + (t & 1) * 32768;
        bf16* bufN = sm + ((t & 1) ^ 1) * 32768;
        int ktn = kS + (t + 1) * 64;
        bool more = (t + 1) < nt;
        // tile boundary: issue FULL next tile (A+B, 8 loads), counted vmcnt(8)
        if (more) {
            stage_half(Ab, lda, ktn, bufN, tid);
            stage_half(Ab + (size_t)128 * lda, lda, ktn, bufN + 8192, tid);
            stage_half(Bb, ldb, ktn, bufN + 16384, tid);
            stage_half(Bb + (size_t)128 * ldb, ldb, ktn, bufN + 24576, tid);
            asm volatile("s_waitcnt vmcnt(8)" ::: "memory");
        } else {
            asm volatile("s_waitcnt vmcnt(0)" ::: "memory");
        }
        __builtin_amdgcn_s_barrier();
        __builtin_amdgcn_sched_barrier(0);
        short8 b0[4], b1[4], a0[4], a1[4], a2[4], a3[4];
#pragma unroll
        for (int n = 0; n < 4; n++) {
            b0[n] = RD(bBase + n * 1024 + cb0);
            b1[n] = RD(bBase + n * 1024 + cb1);
        }
        LOADA(a0, 0)
        LOADA(a1, 2)
        __builtin_amdgcn_sched_barrier(0);
        CLUST(0, a0)
        LOADA(a2, 4)
        PBAR
        CLUST(2, a1)
        LOADA(a3, 6)
        PBAR
        CLUST(4, a2)
        PBAR
        CLUST(6, a3)
        PBAR
    }

    // epilogue: bf16 store, exact dims
    int rb = row0 + wm * 128 + lk4 * 4;
    int cbase = col0 + wn * 64 + lr;
#pragma unroll
    for (int fm = 0; fm < 8; fm++)
#pragma unroll
        for (int n = 0; n < 4; n++)
#pragma unroll
            for (int j = 0; j < 4; j++)
                C[(size_t)(rb + fm * 16 + j) * ldc + cbase + n * 16] = f2b(acc[fm][n][j]);
}

// combo: blocks [0,nb0) run job0 (B2inv), [nb0,total) run job1 (DFT).
__global__ __launch_bounds__(512, 2) void gemm8p_combo(
        const bf16* A0, int lda0, const bf16* B0, int ldb0, bf16* C0, int ldc0,
        int gx0, int nt0, int nb0,
        const bf16* A1, int lda1, const bf16* B1w, int ldb1, bf16* C1, int ldc1,
        int gx1, int nt1) {
    __shared__ bf16 sm[65536];
    int id = blockIdx.x;
    bool p0 = id < nb0;
    const bf16* A = p0 ? A0 : A1; int lda = p0 ? lda0 : lda1;
    const bf16* B = p0 ? B0 : B1w; int ldb = p0 ? ldb0 : ldb1;
    bf16* C = p0 ? C0 : C1; int ldc = p0 ? ldc0 : ldc1;
    int gx = p0 ? gx0 : gx1, nt = p0 ? nt0 : nt1;
    int id2 = p0 ? id : id - nb0;
    int bx = id2 % gx, by = id2 / gx;
    gemm8p_body(sm, A, lda, B, ldb, C, ldc, by * 256, bx * 256, 0, nt);
}

// L2: 256 blocks, XCD-bijective (4x,16y,4z) mapping, z slices K.
__global__ __launch_bounds__(512, 2) void gemm8p_l2(
        const bf16* __restrict__ A, int lda, const bf16* __restrict__ B, int ldb,
        bf16* __restrict__ C, int ldc, size_t zCoff, int tilesPerZ) {
    __shared__ bf16 sm[65536];
    int id = blockIdx.x;
    int by_z = (id & 7) * 8 + (id >> 5);
    int bx = (id >> 3) & 3;
    int z = by_z >> 4;
    int by = by_z & 15;
    gemm8p_body(sm, A, lda, B, ldb, C + (size_t)z * zCoff, ldc,
                by * 256, bx * 256, z * tilesPerZ * 64, tilesPerZ);
}

// ---------------------------------------------------------------------------
extern "C" void kernel_launch(void* const* d_in, const int* in_sizes, int n_in,
                              void* d_out, int out_size, void* d_ws, size_t ws_size,
                              hipStream_t stream) {
    const float* X   = (const float*)d_in[0];
    const float* bp  = (const float*)d_in[1];
    const float* W1r = (const float*)d_in[2];
    const float* W1i = (const float*)d_in[3];
    const float* b1r = (const float*)d_in[4];
    const float* b1i = (const float*)d_in[5];
    const float* W2r = (const float*)d_in[6];
    const float* W2i = (const float*)d_in[7];
    const float* b2r = (const float*)d_in[8];
    const float* b2i = (const float*)d_in[9];
    const float* gW  = (const float*)d_in[10];
    const float* gb  = (const float*)d_in[11];
    float* out = (float*)d_out;

    const size_t SZH = (size_t)MR * HP_LD * 2;   // 136.3 MB total for Hp

    // ---- carve workspace (~267.5 MB; proven budget from R6)
    char* p = (char*)d_ws;
    auto alloc = [&](size_t bytes) -> char* {
        char* r = p; p += (bytes + 255) & ~255ULL; return r;
    };
    int*   se     = (int*)alloc(64 * 4);
    float* magp   = (float*)alloc((size_t)BATCH * 8 * MAG_LD * 4);
    float* gate   = (float*)alloc((size_t)BATCH * NE * 4);
    float* biasCs = (float*)alloc((size_t)BATCH * BIAS_LD * 4);
    float* biasT  = (float*)alloc((size_t)BATCH * NN * 4);
    bf16*  Ffwd   = (bf16*)alloc((size_t)FF_ROWS * NN * 2);
    bf16*  Finv   = (bf16*)alloc((size_t)NN * FINV_LD * 2);
    // B1 slot (44.6 MB): B1 through L1, then L2 output planes (33.6 MB)
    char*  b1slot = alloc((size_t)NE * B1_ROWS * XINT_LD * 2);
    bf16*  B1     = (bf16*)b1slot;
    bf16*  planesB = (bf16*)b1slot;
    bf16*  B2t    = (bf16*)alloc((size_t)KCAT * FINV_LD * 2);
    bf16*  Xint   = (bf16*)alloc((size_t)MR * XINT_LD * 2);
    bf16*  B2inv  = (bf16*)alloc((size_t)NN * KCAT * 2);       // own slot (34.1 MB)
    bf16*  Hp     = (bf16*)alloc(8 * SZH);
    bf16*  Xb     = (bf16*)((char*)Hp + 8 * SZH - (size_t)MR * NN * 2);  // Hp tail

    // ---- prep (se first; prep_all = elementwise + B2t transpose tail blocks)
    prep_kernel<<<1, 64, 0, stream>>>(bp, se);
    prep_all<<<NB_BULK + NB_B2T, 256, 0, stream>>>(
        W1r, W1i, W2r, W2i, X, se, Ffwd, Finv, B1, B2t, Xb);

    // ---- combo: B2inv[1024][16640] = Finv * B2t^T (260 blocks)
    //           ∥ DFT: Xint[4096][1280] = Xb * Ffwd^T  (80 blocks)
    gemm8p_combo<<<340, 512, 0, stream>>>(
        Finv, FINV_LD, B2t, FINV_LD, B2inv, KCAT, 65, 17, 260,
        Xb, NN, Ffwd, NN, Xint, XINT_LD, 5, 16);

    // ---- gate path (mag partials -> gate+biasCs -> biasT)
    mag_kernel<<<dim3(BATCH, 8), 256, 0, stream>>>(Xint, magp);
    gate_bias_kernel<<<BATCH, 256, 0, stream>>>(magp, gW, gb, b2r, b2i, gate, biasCs);
    biasT_kernel<<<dim3(16, BATCH), 256, 0, stream>>>(biasCs, Ffwd, biasT);

    // ---- L1 (all 8 experts, gate folded): Hp[4096][16640]  (B1 still intact)
    gemm_mfma<1><<<dim3(17, 32, 8), 256, 0, stream>>>(
        Xint, XINT_LD, B1, XINT_LD, (size_t)B1_ROWS * XINT_LD,
        Hp, KCAT, HP_LD, 2 * HD, 0, 0,
        se, b1r, b1i, HD, gate);

    // ---- L2+iDFT fused: plane_z = Hp * B2inv^T over z's K-slice
    //      (planes live in B1's slot — B1 dead after L1)
    gemm8p_l2<<<256, 512, 0, stream>>>(
        Hp, KCAT, B2inv, KCAT, planesB, NN, (size_t)MR * NN, 65);

    // ---- reduce 4 planes + biasT -> out
    reduce_out4<<<(unsigned)(((size_t)MR * NN / 8 + 255) / 256), 256, 0, stream>>>(
        planesB, biasT, out);
}

// Round 14
// 411.342 us; speedup vs baseline: 1.0534x; 1.0534x over previous
//
#include <hip/hip_runtime.h>
#include <hip/hip_bf16.h>
#include <math.h>

typedef __hip_bfloat16 bf16;
typedef __attribute__((ext_vector_type(8))) short short8;
typedef __attribute__((ext_vector_type(4))) float f32x4;

#define FB 513
#define HD 1026
#define NN 1024
#define MR 4096      // 32*128 rows
#define NE 8
#define BATCH 32

#define XINT_LD 1280   // 2*FB padded to 5*256 (DFT gemm8p N)
#define BIAS_LD 1056
#define FINV_LD 1088   // 17*64 (Finv / B2t K-stride)
#define HP_LD   2080   // per-expert window in H'
#define B1_ROWS 2176
#define KCAT    16640  // 8*2080
#define MAG_LD  520
#define FF_ROWS 1280

__device__ __forceinline__ void gload16(const void* g, void* l) {
    __builtin_amdgcn_global_load_lds((const __attribute__((address_space(1))) void*)g,
                                     (__attribute__((address_space(3))) void*)l, 16, 0, 0);
}
__device__ __forceinline__ bf16 f2b(float v) { return __float2bfloat16(v); }
__device__ __forceinline__ unsigned short f2bu(float v) {
    bf16 b = __float2bfloat16(v);
    return *reinterpret_cast<unsigned short*>(&b);
}
__device__ __forceinline__ float bu2f(unsigned short u) {
    return __uint_as_float(((unsigned)u) << 16);
}
__device__ __forceinline__ unsigned pack2(float a, float b) {
    return (unsigned)f2bu(a) | ((unsigned)f2bu(b) << 16);
}

// XCD-aware bijective remap for the 128^2 kernel (grid.x*grid.y % 8 == 0)
__device__ __forceinline__ void xcd_swizzle(int* px, int* py) {
    int gx = gridDim.x;
    int orig = blockIdx.x + gx * blockIdx.y;
    int q = (gx * gridDim.y) >> 3;
    int wg = (orig & 7) * q + (orig >> 3);
    *px = wg % gx;
    *py = wg / gx;
}

// ---------------------------------------------------------------------------
__global__ void prep_kernel(const float* __restrict__ bp, int* __restrict__ se) {
    if (threadIdx.x == 0 && blockIdx.x == 0) {
        float b[9];
        b[0] = 0.0f; b[8] = 1.0f;
        for (int i = 0; i < 7; i++) b[i + 1] = 1.0f / (1.0f + expf(-bp[i]));
        for (int i = 1; i < 9; i++) { float v = b[i]; int j = i - 1;
            while (j >= 0 && b[j] > v) { b[j + 1] = b[j]; j--; } b[j + 1] = v; }
        int idx[9];
        for (int i = 0; i < 9; i++) idx[i] = (int)(b[i] * (float)(FB - 1));
        for (int e = 0; e < NE; e++) {
            se[2 * e] = idx[e];
            se[2 * e + 1] = (e < NE - 1) ? idx[e + 1] : FB;
        }
    }
}

// ---------------------------------------------------------------------------
// prep_all: blocks [0, NB_BULK) elementwise [Ffwd | Finv | B1 | X];
//           blocks [NB_BULK, +1224) = LDS-tiled B2t transpose.
// ---------------------------------------------------------------------------
#define N_FF  ((long)FF_ROWS * NN)                // 1,310,720
#define N_FI  (1024L * FINV_LD)                   // 1,114,112
#define N_B1P ((long)NE * B1_ROWS * (XINT_LD / 2))// 11,141,120
#define N_XP  ((long)MR * NN / 2)                 // 2,097,152
#define N_PREP (N_FF + N_FI + N_B1P + N_XP)       // 15,663,104 = 61184*256
#define NB_BULK 61184
#define NB_B2T  1224                              // 9*17*8

__global__ void prep_all(const float* __restrict__ W1r, const float* __restrict__ W1i,
                         const float* __restrict__ W2r, const float* __restrict__ W2i,
                         const float* __restrict__ X, const int* __restrict__ se,
                         bf16* __restrict__ Ffwd, bf16* __restrict__ Finv,
                         bf16* __restrict__ B1, bf16* __restrict__ B2t,
                         bf16* __restrict__ Xb) {
    __shared__ float sR[64][65], sI[64][65];
    int tid = threadIdx.x;
    if (blockIdx.x >= NB_BULK) {
        // ---- B2t transpose path
        int bid2 = blockIdx.x - NB_BULK;
        int fx = bid2 % 9;
        int hy = (bid2 / 9) % 17;
        int e = bid2 / 153;
        int f0 = fx * 64, h0 = hy * 64;
#pragma unroll
        for (int rep = 0; rep < 16; rep++) {
            int idx = tid + rep * 256;
            int fl = idx >> 6, hl = idx & 63;
            int f = f0 + fl, h = h0 + hl;
            bool ok = (f < FB) && (h < HD);
            size_t wi = ((size_t)e * FB + f) * HD + h;
            sR[fl][hl] = ok ? W2r[wi] : 0.0f;
            sI[fl][hl] = ok ? W2i[wi] : 0.0f;
        }
        __syncthreads();
#pragma unroll
        for (int rep = 0; rep < 4; rep++) {
            int idx = tid + rep * 256;
            int hl = idx >> 4, ch = idx & 15;
            int h = h0 + hl;
            int c0 = 2 * f0 + ch * 8;
            if (c0 >= FINV_LD) continue;
            short8 lo, hi;
#pragma unroll
            for (int j = 0; j < 4; j++) {
                int fl = ch * 4 + j;
                float wr = sR[fl][hl], wim = sI[fl][hl];
                lo[2 * j]     = (short)f2bu(wr);
                lo[2 * j + 1] = (short)f2bu(wim);
                hi[2 * j]     = (short)f2bu(-wim);
                hi[2 * j + 1] = (short)f2bu(wr);
            }
            if (h < HD) {
                *(short8*)(B2t + ((size_t)e * HP_LD + h) * FINV_LD + c0) = lo;
                *(short8*)(B2t + ((size_t)e * HP_LD + HD + h) * FINV_LD + c0) = hi;
            } else if (HD + h < HP_LD) {
                short8 z = {};
                *(short8*)(B2t + ((size_t)e * HP_LD + HD + h) * FINV_LD + c0) = z;
            }
        }
        return;
    }
    long i = (long)blockIdx.x * 256 + tid;
    const float TWO_PI = 6.283185307179586f;
    if (i < N_FF) {                 // Ffwd: rows 2f=cos, 2f+1=-sin; rows>=1026 zero
        int n = (int)(i >> 10), t = (int)(i & (NN - 1));
        float v = 0.0f;
        if (n < 2 * FB) {
            int f = n >> 1, k = (f * t) & (NN - 1);
            float s, c; sincosf(TWO_PI * (float)k / (float)NN, &s, &c);
            v = (n & 1) ? -s : c;
        }
        Ffwd[i] = f2b(v);
        return;
    }
    i -= N_FF;
    if (i < N_FI) {                 // Finv[1024][1088]
        int t = (int)(i / FINV_LD), k = (int)(i % FINV_LD);
        float v = 0.0f;
        if (k < 2 * FB) {
            int f = k >> 1, kk = (f * t) & (NN - 1);
            float s, c; sincosf(TWO_PI * (float)kk / (float)NN, &s, &c);
            float cf = (f == 0 || f == FB - 1) ? 1.0f : 2.0f;
            float sc = cf * (1.0f / (float)NN);
            v = (k & 1) ? -s * sc : c * sc;
        }
        Finv[i] = f2b(v);
        return;
    }
    i -= N_FI;
    if (i < N_B1P) {                // B1[e][2176][1280], pair (2f,2f+1)/thread
        int f = (int)(i % (XINT_LD / 2));
        long t = i / (XINT_LD / 2);
        int n = (int)(t % B1_ROWS);
        int e = (int)(t / B1_ROWS);
        float ve = 0.0f, vo = 0.0f;
        if (n < 2 * HD && f < FB && f >= se[2 * e] && f < se[2 * e + 1]) {
            int hi_part = (n >= HD);
            int h = hi_part ? n - HD : n;
            long wi = ((long)e * HD + h) * FB + f;
            float wr = W1r[wi], wim = W1i[wi];
            ve = hi_part ? wim : wr;
            vo = hi_part ? wr : -wim;
        }
        *(unsigned*)(B1 + ((size_t)(e * B1_ROWS + n)) * XINT_LD + 2 * f) = pack2(ve, vo);
        return;
    }
    i -= N_B1P;
    if (i < N_XP) {                 // X fp32 -> bf16, paired
        float2 v = ((const float2*)X)[i];
        *(unsigned*)(Xb + 2 * i) = pack2(v.x, v.y);
    }
}

// ---------------------------------------------------------------------------
__global__ void mag_kernel(const bf16* __restrict__ Xint, float* __restrict__ magp) {
    int b = blockIdx.x, g = blockIdx.y, t = threadIdx.x;
    float acc[3] = {0.0f, 0.0f, 0.0f};
    const bf16* base = Xint + ((size_t)b * 128 + g * 16) * XINT_LD;
    for (int c = 0; c < 16; c++) {
        const bf16* row = base + (size_t)c * XINT_LD;
#pragma unroll
        for (int kk = 0; kk < 3; kk++) {
            int f = t + 256 * kk;
            if (f < FB) {
                float xr = __bfloat162float(row[2 * f]);
                float xi = __bfloat162float(row[2 * f + 1]);
                acc[kk] += sqrtf(xr * xr + xi * xi);
            }
        }
    }
#pragma unroll
    for (int kk = 0; kk < 3; kk++) {
        int f = t + 256 * kk;
        if (f < FB) magp[((size_t)b * 8 + g) * MAG_LD + f] = acc[kk];
    }
}

// ---------------------------------------------------------------------------
// gate + scaled gated-bias: biasCs[b][c] = (c_f/N)*sum_e g_e*b2[e][f]
// ---------------------------------------------------------------------------
__global__ void gate_bias_kernel(const float* __restrict__ magp, const float* __restrict__ gW,
                                 const float* __restrict__ gb, const float* __restrict__ b2r,
                                 const float* __restrict__ b2i, float* __restrict__ gate,
                                 float* __restrict__ biasCs) {
    __shared__ float sred[256];
    __shared__ float sg[8];
    int b = blockIdx.x, tid = threadIdx.x;
    int e = tid & 7, j = tid >> 3;
    float acc = 0.0f;
    for (int f = j; f < FB; f += 32) {
        float m = 0.0f;
#pragma unroll
        for (int g = 0; g < 8; g++) m += magp[((size_t)b * 8 + g) * MAG_LD + f];
        acc += m * (1.0f / 128.0f) * gW[e * FB + f];
    }
    sred[tid] = acc;
    __syncthreads();
    if (tid < 64) {
        float a = sred[tid] + sred[tid + 64] + sred[tid + 128] + sred[tid + 192];
        a += __shfl_xor(a, 8); a += __shfl_xor(a, 16); a += __shfl_xor(a, 32);
        float logit = a + gb[e];
        float mx = logit;
        mx = fmaxf(mx, __shfl_xor(mx, 1)); mx = fmaxf(mx, __shfl_xor(mx, 2)); mx = fmaxf(mx, __shfl_xor(mx, 4));
        float ex = expf(logit - mx);
        float sum = ex;
        sum += __shfl_xor(sum, 1); sum += __shfl_xor(sum, 2); sum += __shfl_xor(sum, 4);
        if (tid < 8) { float g_ = ex / sum; sg[tid] = g_; gate[b * NE + tid] = g_; }
    }
    __syncthreads();
    for (int c = tid; c < BIAS_LD; c += 256) {
        float v = 0.0f;
        if (c < 2 * FB) {
            int f = c >> 1;
            const float* bb = (c & 1) ? b2i : b2r;
#pragma unroll
            for (int ee = 0; ee < NE; ee++) v += sg[ee] * bb[ee * FB + f];
            float cf = (f == 0 || f == FB - 1) ? 1.0f : 2.0f;
            v *= cf * (1.0f / (float)NN);
        }
        biasCs[b * BIAS_LD + c] = v;
    }
}

// ---------------------------------------------------------------------------
// biasT[b][t] = sum_c biasCs[b][c]*Ffwd[c][t]. Grid (16, BATCH), 512 blocks.
// ---------------------------------------------------------------------------
__global__ void biasT_kernel(const float* __restrict__ biasCs, const bf16* __restrict__ Ffwd,
                             float* __restrict__ biasT) {
    __shared__ float red[256];
    int b = blockIdx.y;
    int t = blockIdx.x * 64 + (threadIdx.x & 63);
    int part = threadIdx.x >> 6;       // 0..3
    float s = 0.0f;
    for (int c = part; c < 2 * FB; c += 4)
        s += biasCs[b * BIAS_LD + c] * __bfloat162float(Ffwd[(size_t)c * NN + t]);
    red[threadIdx.x] = s;
    __syncthreads();
    if (threadIdx.x < 64) {
        float v = red[threadIdx.x] + red[threadIdx.x + 64] +
                  red[threadIdx.x + 128] + red[threadIdx.x + 192];
        biasT[b * NN + t] = v;
    }
}

// ---------------------------------------------------------------------------
// out[r][t] = sum_z bf16plane_z[r][t] + biasT[r>>7][t]
// ---------------------------------------------------------------------------
__global__ void reduce_out4(const bf16* __restrict__ planes, const float* __restrict__ biasT,
                            float* __restrict__ out) {
    long idx = (long)blockIdx.x * 256 + threadIdx.x;
    if (idx >= (long)MR * NN / 8) return;
    size_t base = (size_t)idx * 8;
    long r = base >> 10;
    int t = (int)(base & (NN - 1));
    float s[8] = {};
#pragma unroll
    for (int z = 0; z < 4; z++) {
        short8 v = *(const short8*)(planes + (size_t)z * MR * NN + base);
#pragma unroll
        for (int j = 0; j < 8; j++) s[j] += bu2f((unsigned short)v[j]);
    }
    const float* bT = biasT + (r >> 7) * NN + t;
    float4 o0 = {s[0] + bT[0], s[1] + bT[1], s[2] + bT[2], s[3] + bT[3]};
    float4 o1 = {s[4] + bT[4], s[5] + bT[5], s[6] + bT[6], s[7] + bT[7]};
    *(float4*)(out + base) = o0;
    *(float4*)(out + base + 4) = o1;
}

// ---------------------------------------------------------------------------
// 128^2 MFMA GEMM (L1 only): EPI1 = relu(acc+bias)*gate -> bf16, per-z expert
// ---------------------------------------------------------------------------
template <int EPI>
__global__ void gemm_mfma(const bf16* __restrict__ A, int lda,
                          const bf16* __restrict__ B, int ldb, size_t zBstride,
                          void* __restrict__ Cv, int ldc, size_t zCoff,
                          int N, int K, int kPerZ,
                          const int* __restrict__ se2,
                          const float* __restrict__ biasR, const float* __restrict__ biasI,
                          int zBias, const float* __restrict__ gate8) {
    __shared__ bf16 As[128 * 32];
    __shared__ bf16 Bs[128 * 32];
    int tid = threadIdx.x;
    int zz = blockIdx.z;
    int bx, by;
    xcd_swizzle(&bx, &by);
    int row0 = by * 128, col0 = bx * 128;
    const bf16* Bz = B + (size_t)zz * zBstride;

    int kS, kE;
    if (EPI == 1) { int s = se2[2 * zz], e = se2[2 * zz + 1]; kS = (2 * s) & ~31; kE = (2 * e + 31) & ~31; }
    else          { kS = zz * kPerZ; kE = min(K, kS + kPerZ); }

    f32x4 acc[4][4] = {};

    int lane = tid & 63, wid = tid >> 6;
    int wrB = (wid >> 1) << 6, wcB = (wid & 1) << 6;
    int lr = lane & 15, lk = (lane >> 4) << 3;

    int r_a = tid >> 2, c_a = (tid & 3) << 3;
    int r_b = (tid + 256) >> 2, c_b = ((tid + 256) & 3) << 3;

    for (int kt = kS; kt < kE; kt += 32) {
        gload16(A + (size_t)(row0 + r_a) * lda + kt + c_a, &As[(size_t)tid * 8]);
        gload16(A + (size_t)(row0 + r_b) * lda + kt + c_b, &As[((size_t)tid + 256) * 8]);
        gload16(Bz + (size_t)(col0 + r_a) * ldb + kt + c_a, &Bs[(size_t)tid * 8]);
        gload16(Bz + (size_t)(col0 + r_b) * ldb + kt + c_b, &Bs[((size_t)tid + 256) * 8]);
        __syncthreads();
        short8 av[4], bv[4];
#pragma unroll
        for (int m = 0; m < 4; m++)
            av[m] = *(const short8*)&As[(wrB + m * 16 + lr) * 32 + lk];
#pragma unroll
        for (int n = 0; n < 4; n++)
            bv[n] = *(const short8*)&Bs[(wcB + n * 16 + lr) * 32 + lk];
#pragma unroll
        for (int m = 0; m < 4; m++)
#pragma unroll
            for (int n = 0; n < 4; n++)
                acc[m][n] = __builtin_amdgcn_mfma_f32_16x16x32_bf16(av[m], bv[n], acc[m][n], 0, 0, 0);
        __syncthreads();
    }

    int r0 = row0 + wrB + ((lane >> 4) << 2);
    int c0i = col0 + wcB + (lane & 15);
    float g = (EPI == 1) ? gate8[(row0 >> 7) * NE + zz] : 0.0f;

#pragma unroll
    for (int m = 0; m < 4; m++)
#pragma unroll
        for (int n = 0; n < 4; n++) {
            int c = c0i + n * 16;
            if (c >= N) continue;
#pragma unroll
            for (int j = 0; j < 4; j++) {
                int r = r0 + m * 16 + j;
                float v = acc[m][n][j];
                if (EPI == 1) {
                    v += (c < HD) ? biasR[zz * zBias + c] : biasI[zz * zBias + c - HD];
                    v = fmaxf(v, 0.0f) * g;
                    ((bf16*)Cv + (size_t)zz * zCoff)[(size_t)r * ldc + c] = f2b(v);
                } else {
                    ((float*)Cv + (size_t)zz * zCoff)[(size_t)r * ldc + c] = v;
                }
            }
        }
}

// ---------------------------------------------------------------------------
// 8-phase 256x256 GEMM body — R10-proven schedule (best measured: 125-126 us):
// A-halves staged at iter top + counted vmcnt(4); B-halves staged after
// CLUST(0) under compute; A-frag ds_reads pipelined one phase ahead.
// ---------------------------------------------------------------------------
__device__ __forceinline__ void stage_half(const bf16* gbase, int ld, int kt,
                                           bf16* ldsBase, int tid) {
#pragma unroll
    for (int j = 0; j < 2; j++) {
        int r = j * 64 + (tid >> 3);
        int sc = ((tid & 7) ^ ((tid >> 3) & 7)) * 8;
        gload16(gbase + (size_t)r * ld + kt + sc, ldsBase + j * 4096 + tid * 8);
    }
}

#define MF(a, b, c) __builtin_amdgcn_mfma_f32_16x16x32_bf16(a, b, c, 0, 0, 0)
#define RD(off) (*(const short8*)(bc + (off)))
#define LOADA(dst, FM)                                                        \
    dst[0] = RD(aBase + (FM) * 1024 + cb0);                                   \
    dst[1] = RD(aBase + (FM) * 1024 + cb1);                                   \
    dst[2] = RD(aBase + (FM + 1) * 1024 + cb0);                               \
    dst[3] = RD(aBase + (FM + 1) * 1024 + cb1);
#define CLUST(FM, av)                                                         \
    __builtin_amdgcn_s_setprio(1);                                            \
    acc[FM][0] = MF(av[0], b0[0], acc[FM][0]);                                \
    acc[FM][0] = MF(av[1], b1[0], acc[FM][0]);                                \
    acc[FM][1] = MF(av[0], b0[1], acc[FM][1]);                                \
    acc[FM][1] = MF(av[1], b1[1], acc[FM][1]);                                \
    acc[FM][2] = MF(av[0], b0[2], acc[FM][2]);                                \
    acc[FM][2] = MF(av[1], b1[2], acc[FM][2]);                                \
    acc[FM][3] = MF(av[0], b0[3], acc[FM][3]);                                \
    acc[FM][3] = MF(av[1], b1[3], acc[FM][3]);                                \
    acc[FM + 1][0] = MF(av[2], b0[0], acc[FM + 1][0]);                        \
    acc[FM + 1][0] = MF(av[3], b1[0], acc[FM + 1][0]);                        \
    acc[FM + 1][1] = MF(av[2], b0[1], acc[FM + 1][1]);                        \
    acc[FM + 1][1] = MF(av[3], b1[1], acc[FM + 1][1]);                        \
    acc[FM + 1][2] = MF(av[2], b0[2], acc[FM + 1][2]);                        \
    acc[FM + 1][2] = MF(av[3], b1[2], acc[FM + 1][2]);                        \
    acc[FM + 1][3] = MF(av[2], b0[3], acc[FM + 1][3]);                        \
    acc[FM + 1][3] = MF(av[3], b1[3], acc[FM + 1][3]);                        \
    __builtin_amdgcn_s_setprio(0);
#define PBAR { __builtin_amdgcn_sched_barrier(0); __builtin_amdgcn_s_barrier(); }

__device__ __forceinline__ void gemm8p_body(
        bf16* sm, const bf16* __restrict__ A, int lda,
        const bf16* __restrict__ B, int ldb,
        bf16* __restrict__ C, int ldc,
        int row0, int col0, int kS, int nt) {
    int tid = threadIdx.x;
    const bf16* Ab = A + (size_t)row0 * lda;
    const bf16* Bb = B + (size_t)col0 * ldb;

    // prologue: stage tile 0 into buf0
    stage_half(Ab, lda, kS, sm, tid);
    stage_half(Ab + (size_t)128 * lda, lda, kS, sm + 8192, tid);
    stage_half(Bb, ldb, kS, sm + 16384, tid);
    stage_half(Bb + (size_t)128 * ldb, ldb, kS, sm + 24576, tid);

    f32x4 acc[8][4] = {};

    int l = tid & 63, w = tid >> 6;
    int wm = w >> 2, wn = w & 3;
    int lr = l & 15, lk4 = l >> 4;
    int swz = lr & 7;
    int cb0 = ((lk4) ^ swz) * 8;
    int cb1 = ((4 + lk4) ^ swz) * 8;
    int aBase = wm * 8192 + lr * 64;
    int bBase = 16384 + (wn >> 1) * 8192 + (wn & 1) * 4096 + lr * 64;

    for (int t = 0; t < nt; ++t) {
        const bf16* bc = sm + (t & 1) * 32768;
        bf16* bufN = sm + ((t & 1) ^ 1) * 32768;
        int ktn = kS + (t + 1) * 64;
        bool more = (t + 1) < nt;
        // tile boundary: stage A halves of t+1, counted vmcnt, barrier
        if (more) {
            stage_half(Ab, lda, ktn, bufN, tid);
            stage_half(Ab + (size_t)128 * lda, lda, ktn, bufN + 8192, tid);
            asm volatile("s_waitcnt vmcnt(4)" ::: "memory");
        } else {
            asm volatile("s_waitcnt vmcnt(0)" ::: "memory");
        }
        __builtin_amdgcn_s_barrier();
        __builtin_amdgcn_sched_barrier(0);
        short8 b0[4], b1[4], a0[4], a1[4], a2[4], a3[4];
#pragma unroll
        for (int n = 0; n < 4; n++) {
            b0[n] = RD(bBase + n * 1024 + cb0);
            b1[n] = RD(bBase + n * 1024 + cb1);
        }
        LOADA(a0, 0)
        LOADA(a1, 2)
        __builtin_amdgcn_sched_barrier(0);
        CLUST(0, a0)
        if (more) {                  // stage B halves of t+1 under compute
            stage_half(Bb, ldb, ktn, bufN + 16384, tid);
            stage_half(Bb + (size_t)128 * ldb, ldb, ktn, bufN + 24576, tid);
        }
        LOADA(a2, 4)
        PBAR
        CLUST(2, a1)
        LOADA(a3, 6)
        PBAR
        CLUST(4, a2)
        PBAR
        CLUST(6, a3)
        PBAR
    }

    // epilogue: bf16 store, exact dims
    int rb = row0 + wm * 128 + lk4 * 4;
    int cbase = col0 + wn * 64 + lr;
#pragma unroll
    for (int fm = 0; fm < 8; fm++)
#pragma unroll
        for (int n = 0; n < 4; n++)
#pragma unroll
            for (int j = 0; j < 4; j++)
                C[(size_t)(rb + fm * 16 + j) * ldc + cbase + n * 16] = f2b(acc[fm][n][j]);
}

// combo: blocks [0,nb0) run job0 (B2inv), [nb0,total) run job1 (DFT).
__global__ __launch_bounds__(512, 2) void gemm8p_combo(
        const bf16* A0, int lda0, const bf16* B0, int ldb0, bf16* C0, int ldc0,
        int gx0, int nt0, int nb0,
        const bf16* A1, int lda1, const bf16* B1w, int ldb1, bf16* C1, int ldc1,
        int gx1, int nt1) {
    __shared__ bf16 sm[65536];
    int id = blockIdx.x;
    bool p0 = id < nb0;
    const bf16* A = p0 ? A0 : A1; int lda = p0 ? lda0 : lda1;
    const bf16* B = p0 ? B0 : B1w; int ldb = p0 ? ldb0 : ldb1;
    bf16* C = p0 ? C0 : C1; int ldc = p0 ? ldc0 : ldc1;
    int gx = p0 ? gx0 : gx1, nt = p0 ? nt0 : nt1;
    int id2 = p0 ? id : id - nb0;
    int bx = id2 % gx, by = id2 / gx;
    gemm8p_body(sm, A, lda, B, ldb, C, ldc, by * 256, bx * 256, 0, nt);
}

// L2: 256 blocks, XCD-bijective (4x,16y,4z) mapping, z slices K.
__global__ __launch_bounds__(512, 2) void gemm8p_l2(
        const bf16* __restrict__ A, int lda, const bf16* __restrict__ B, int ldb,
        bf16* __restrict__ C, int ldc, size_t zCoff, int tilesPerZ) {
    __shared__ bf16 sm[65536];
    int id = blockIdx.x;
    int by_z = (id & 7) * 8 + (id >> 5);
    int bx = (id >> 3) & 3;
    int z = by_z >> 4;
    int by = by_z & 15;
    gemm8p_body(sm, A, lda, B, ldb, C + (size_t)z * zCoff, ldc,
                by * 256, bx * 256, z * tilesPerZ * 64, tilesPerZ);
}

// ---------------------------------------------------------------------------
extern "C" void kernel_launch(void* const* d_in, const int* in_sizes, int n_in,
                              void* d_out, int out_size, void* d_ws, size_t ws_size,
                              hipStream_t stream) {
    const float* X   = (const float*)d_in[0];
    const float* bp  = (const float*)d_in[1];
    const float* W1r = (const float*)d_in[2];
    const float* W1i = (const float*)d_in[3];
    const float* b1r = (const float*)d_in[4];
    const float* b1i = (const float*)d_in[5];
    const float* W2r = (const float*)d_in[6];
    const float* W2i = (const float*)d_in[7];
    const float* b2r = (const float*)d_in[8];
    const float* b2i = (const float*)d_in[9];
    const float* gW  = (const float*)d_in[10];
    const float* gb  = (const float*)d_in[11];
    float* out = (float*)d_out;

    const size_t SZH = (size_t)MR * HP_LD * 2;   // 136.3 MB total for Hp

    // ---- carve workspace (~267.5 MB; proven budget from R6)
    char* p = (char*)d_ws;
    auto alloc = [&](size_t bytes) -> char* {
        char* r = p; p += (bytes + 255) & ~255ULL; return r;
    };
    int*   se     = (int*)alloc(64 * 4);
    float* magp   = (float*)alloc((size_t)BATCH * 8 * MAG_LD * 4);
    float* gate   = (float*)alloc((size_t)BATCH * NE * 4);
    float* biasCs = (float*)alloc((size_t)BATCH * BIAS_LD * 4);
    float* biasT  = (float*)alloc((size_t)BATCH * NN * 4);
    bf16*  Ffwd   = (bf16*)alloc((size_t)FF_ROWS * NN * 2);
    bf16*  Finv   = (bf16*)alloc((size_t)NN * FINV_LD * 2);
    // B1 slot (44.6 MB): B1 through L1, then L2 output planes (33.6 MB)
    char*  b1slot = alloc((size_t)NE * B1_ROWS * XINT_LD * 2);
    bf16*  B1     = (bf16*)b1slot;
    bf16*  planesB = (bf16*)b1slot;
    bf16*  B2t    = (bf16*)alloc((size_t)KCAT * FINV_LD * 2);
    bf16*  Xint   = (bf16*)alloc((size_t)MR * XINT_LD * 2);
    bf16*  B2inv  = (bf16*)alloc((size_t)NN * KCAT * 2);       // own slot (34.1 MB)
    bf16*  Hp     = (bf16*)alloc(8 * SZH);
    bf16*  Xb     = (bf16*)((char*)Hp + 8 * SZH - (size_t)MR * NN * 2);  // Hp tail

    // ---- prep (se first; prep_all = elementwise + B2t transpose tail blocks)
    prep_kernel<<<1, 64, 0, stream>>>(bp, se);
    prep_all<<<NB_BULK + NB_B2T, 256, 0, stream>>>(
        W1r, W1i, W2r, W2i, X, se, Ffwd, Finv, B1, B2t, Xb);

    // ---- combo: B2inv[1024][16640] = Finv * B2t^T (260 blocks)
    //           ∥ DFT: Xint[4096][1280] = Xb * Ffwd^T  (80 blocks)
    gemm8p_combo<<<340, 512, 0, stream>>>(
        Finv, FINV_LD, B2t, FINV_LD, B2inv, KCAT, 65, 17, 260,
        Xb, NN, Ffwd, NN, Xint, XINT_LD, 5, 16);

    // ---- gate path (mag partials -> gate+biasCs -> biasT)
    mag_kernel<<<dim3(BATCH, 8), 256, 0, stream>>>(Xint, magp);
    gate_bias_kernel<<<BATCH, 256, 0, stream>>>(magp, gW, gb, b2r, b2i, gate, biasCs);
    biasT_kernel<<<dim3(16, BATCH), 256, 0, stream>>>(biasCs, Ffwd, biasT);

    // ---- L1 (all 8 experts, gate folded): Hp[4096][16640]  (B1 still intact)
    gemm_mfma<1><<<dim3(17, 32, 8), 256, 0, stream>>>(
        Xint, XINT_LD, B1, XINT_LD, (size_t)B1_ROWS * XINT_LD,
        Hp, KCAT, HP_LD, 2 * HD, 0, 0,
        se, b1r, b1i, HD, gate);

    // ---- L2+iDFT fused: plane_z = Hp * B2inv^T over z's K-slice
    //      (planes live in B1's slot — B1 dead after L1)
    gemm8p_l2<<<256, 512, 0, stream>>>(
        Hp, KCAT, B2inv, KCAT, planesB, NN, (size_t)MR * NN, 65);

    // ---- reduce 4 planes + biasT -> out
    reduce_out4<<<(unsigned)(((size_t)MR * NN / 8 + 255) / 256), 256, 0, stream>>>(
        planesB, biasT, out);
}

// Round 15
// 395.857 us; speedup vs baseline: 1.0946x; 1.0391x over previous
//
#include <hip/hip_runtime.h>
#include <hip/hip_bf16.h>
#include <math.h>

typedef __hip_bfloat16 bf16;
typedef __attribute__((ext_vector_type(8))) short short8;
typedef __attribute__((ext_vector_type(4))) float f32x4;

#define FB 513
#define HD 1026
#define NN 1024
#define MR 4096      // 32*128 rows
#define NE 8
#define BATCH 32

#define XINT_LD 1280   // 2*FB padded to 5*256 (DFT gemm8p N)
#define BIAS_LD 1056
#define FINV_LD 1088   // 17*64 (Finv / B2t K-stride)
#define HP_LD   2080   // per-expert window in H'
#define B1_ROWS 2176
#define KCAT    16640  // 8*2080
#define MAG_LD  520
#define FF_ROWS 1280

__device__ __forceinline__ void gload16(const void* g, void* l) {
    __builtin_amdgcn_global_load_lds((const __attribute__((address_space(1))) void*)g,
                                     (__attribute__((address_space(3))) void*)l, 16, 0, 0);
}
__device__ __forceinline__ bf16 f2b(float v) { return __float2bfloat16(v); }
__device__ __forceinline__ unsigned short f2bu(float v) {
    bf16 b = __float2bfloat16(v);
    return *reinterpret_cast<unsigned short*>(&b);
}
__device__ __forceinline__ float bu2f(unsigned short u) {
    return __uint_as_float(((unsigned)u) << 16);
}
__device__ __forceinline__ unsigned pack2(float a, float b) {
    return (unsigned)f2bu(a) | ((unsigned)f2bu(b) << 16);
}

// XCD-aware bijective remap for the 128^2 kernel (grid.x*grid.y % 8 == 0)
__device__ __forceinline__ void xcd_swizzle(int* px, int* py) {
    int gx = gridDim.x;
    int orig = blockIdx.x + gx * blockIdx.y;
    int q = (gx * gridDim.y) >> 3;
    int wg = (orig & 7) * q + (orig >> 3);
    *px = wg % gx;
    *py = wg / gx;
}

// ---------------------------------------------------------------------------
__global__ void prep_kernel(const float* __restrict__ bp, int* __restrict__ se) {
    if (threadIdx.x == 0 && blockIdx.x == 0) {
        float b[9];
        b[0] = 0.0f; b[8] = 1.0f;
        for (int i = 0; i < 7; i++) b[i + 1] = 1.0f / (1.0f + expf(-bp[i]));
        for (int i = 1; i < 9; i++) { float v = b[i]; int j = i - 1;
            while (j >= 0 && b[j] > v) { b[j + 1] = b[j]; j--; } b[j + 1] = v; }
        int idx[9];
        for (int i = 0; i < 9; i++) idx[i] = (int)(b[i] * (float)(FB - 1));
        for (int e = 0; e < NE; e++) {
            se[2 * e] = idx[e];
            se[2 * e + 1] = (e < NE - 1) ? idx[e + 1] : FB;
        }
    }
}

// ---------------------------------------------------------------------------
// prep_bulk (NO LDS -> full occupancy): [Ffwd | Finv | B1 pairs | X pairs]
// ---------------------------------------------------------------------------
#define N_FF  ((long)FF_ROWS * NN)                // 1,310,720
#define N_FI  (1024L * FINV_LD)                   // 1,114,112
#define N_B1P ((long)NE * B1_ROWS * (XINT_LD / 2))// 11,141,120
#define N_XP  ((long)MR * NN / 2)                 // 2,097,152
#define N_PREP (N_FF + N_FI + N_B1P + N_XP)       // 15,663,104

__global__ void prep_bulk(const float* __restrict__ W1r, const float* __restrict__ W1i,
                          const float* __restrict__ X, const int* __restrict__ se,
                          bf16* __restrict__ Ffwd, bf16* __restrict__ Finv,
                          bf16* __restrict__ B1, bf16* __restrict__ Xb) {
    long i = (long)blockIdx.x * 256 + threadIdx.x;
    const float TWO_PI = 6.283185307179586f;
    if (i < N_FF) {                 // Ffwd: rows 2f=cos, 2f+1=-sin; rows>=1026 zero
        int n = (int)(i >> 10), t = (int)(i & (NN - 1));
        float v = 0.0f;
        if (n < 2 * FB) {
            int f = n >> 1, k = (f * t) & (NN - 1);
            float s, c; sincosf(TWO_PI * (float)k / (float)NN, &s, &c);
            v = (n & 1) ? -s : c;
        }
        Ffwd[i] = f2b(v);
        return;
    }
    i -= N_FF;
    if (i < N_FI) {                 // Finv[1024][1088]
        int t = (int)(i / FINV_LD), k = (int)(i % FINV_LD);
        float v = 0.0f;
        if (k < 2 * FB) {
            int f = k >> 1, kk = (f * t) & (NN - 1);
            float s, c; sincosf(TWO_PI * (float)kk / (float)NN, &s, &c);
            float cf = (f == 0 || f == FB - 1) ? 1.0f : 2.0f;
            float sc = cf * (1.0f / (float)NN);
            v = (k & 1) ? -s * sc : c * sc;
        }
        Finv[i] = f2b(v);
        return;
    }
    i -= N_FI;
    if (i < N_B1P) {                // B1[e][2176][1280], pair (2f,2f+1)/thread
        int f = (int)(i % (XINT_LD / 2));
        long t = i / (XINT_LD / 2);
        int n = (int)(t % B1_ROWS);
        int e = (int)(t / B1_ROWS);
        float ve = 0.0f, vo = 0.0f;
        if (n < 2 * HD && f < FB && f >= se[2 * e] && f < se[2 * e + 1]) {
            int hi_part = (n >= HD);
            int h = hi_part ? n - HD : n;
            long wi = ((long)e * HD + h) * FB + f;
            float wr = W1r[wi], wim = W1i[wi];
            ve = hi_part ? wim : wr;
            vo = hi_part ? wr : -wim;
        }
        *(unsigned*)(B1 + ((size_t)(e * B1_ROWS + n)) * XINT_LD + 2 * f) = pack2(ve, vo);
        return;
    }
    i -= N_B1P;
    if (i < N_XP) {                 // X fp32 -> bf16, paired
        float2 v = ((const float2*)X)[i];
        *(unsigned*)(Xb + 2 * i) = pack2(v.x, v.y);
    }
}

// ---------------------------------------------------------------------------
// B2t[16640 k][1088 c] via LDS-tiled transpose (coalesced read AND write).
// ---------------------------------------------------------------------------
__global__ void pack_B2t(const float* __restrict__ W2r, const float* __restrict__ W2i,
                         bf16* __restrict__ B2t) {
    __shared__ float sR[64][65], sI[64][65];
    int e = blockIdx.z;
    int f0 = blockIdx.x * 64;
    int h0 = blockIdx.y * 64;
    int tid = threadIdx.x;
#pragma unroll
    for (int rep = 0; rep < 16; rep++) {
        int idx = tid + rep * 256;
        int fl = idx >> 6, hl = idx & 63;
        int f = f0 + fl, h = h0 + hl;
        bool ok = (f < FB) && (h < HD);
        size_t wi = ((size_t)e * FB + f) * HD + h;
        sR[fl][hl] = ok ? W2r[wi] : 0.0f;
        sI[fl][hl] = ok ? W2i[wi] : 0.0f;
    }
    __syncthreads();
#pragma unroll
    for (int rep = 0; rep < 4; rep++) {
        int idx = tid + rep * 256;        // 64 rows x 16 chunks of 8 bf16
        int hl = idx >> 4, ch = idx & 15;
        int h = h0 + hl;
        int c0 = 2 * f0 + ch * 8;
        if (c0 >= FINV_LD) continue;
        short8 lo, hi;
#pragma unroll
        for (int j = 0; j < 4; j++) {
            int fl = ch * 4 + j;
            float wr = sR[fl][hl], wim = sI[fl][hl];
            lo[2 * j]     = (short)f2bu(wr);
            lo[2 * j + 1] = (short)f2bu(wim);
            hi[2 * j]     = (short)f2bu(-wim);
            hi[2 * j + 1] = (short)f2bu(wr);
        }
        if (h < HD) {
            *(short8*)(B2t + ((size_t)e * HP_LD + h) * FINV_LD + c0) = lo;
            *(short8*)(B2t + ((size_t)e * HP_LD + HD + h) * FINV_LD + c0) = hi;
        } else if (HD + h < HP_LD) {
            short8 z = {};
            *(short8*)(B2t + ((size_t)e * HP_LD + HD + h) * FINV_LD + c0) = z;
        }
    }
}

// ---------------------------------------------------------------------------
__global__ void mag_kernel(const bf16* __restrict__ Xint, float* __restrict__ magp) {
    int b = blockIdx.x, g = blockIdx.y, t = threadIdx.x;
    float acc[3] = {0.0f, 0.0f, 0.0f};
    const bf16* base = Xint + ((size_t)b * 128 + g * 16) * XINT_LD;
    for (int c = 0; c < 16; c++) {
        const bf16* row = base + (size_t)c * XINT_LD;
#pragma unroll
        for (int kk = 0; kk < 3; kk++) {
            int f = t + 256 * kk;
            if (f < FB) {
                float xr = __bfloat162float(row[2 * f]);
                float xi = __bfloat162float(row[2 * f + 1]);
                acc[kk] += sqrtf(xr * xr + xi * xi);
            }
        }
    }
#pragma unroll
    for (int kk = 0; kk < 3; kk++) {
        int f = t + 256 * kk;
        if (f < FB) magp[((size_t)b * 8 + g) * MAG_LD + f] = acc[kk];
    }
}

// ---------------------------------------------------------------------------
// gate + scaled gated-bias: biasCs[b][c] = (c_f/N)*sum_e g_e*b2[e][f]
// ---------------------------------------------------------------------------
__global__ void gate_bias_kernel(const float* __restrict__ magp, const float* __restrict__ gW,
                                 const float* __restrict__ gb, const float* __restrict__ b2r,
                                 const float* __restrict__ b2i, float* __restrict__ gate,
                                 float* __restrict__ biasCs) {
    __shared__ float sred[256];
    __shared__ float sg[8];
    int b = blockIdx.x, tid = threadIdx.x;
    int e = tid & 7, j = tid >> 3;
    float acc = 0.0f;
    for (int f = j; f < FB; f += 32) {
        float m = 0.0f;
#pragma unroll
        for (int g = 0; g < 8; g++) m += magp[((size_t)b * 8 + g) * MAG_LD + f];
        acc += m * (1.0f / 128.0f) * gW[e * FB + f];
    }
    sred[tid] = acc;
    __syncthreads();
    if (tid < 64) {
        float a = sred[tid] + sred[tid + 64] + sred[tid + 128] + sred[tid + 192];
        a += __shfl_xor(a, 8); a += __shfl_xor(a, 16); a += __shfl_xor(a, 32);
        float logit = a + gb[e];
        float mx = logit;
        mx = fmaxf(mx, __shfl_xor(mx, 1)); mx = fmaxf(mx, __shfl_xor(mx, 2)); mx = fmaxf(mx, __shfl_xor(mx, 4));
        float ex = expf(logit - mx);
        float sum = ex;
        sum += __shfl_xor(sum, 1); sum += __shfl_xor(sum, 2); sum += __shfl_xor(sum, 4);
        if (tid < 8) { float g_ = ex / sum; sg[tid] = g_; gate[b * NE + tid] = g_; }
    }
    __syncthreads();
    for (int c = tid; c < BIAS_LD; c += 256) {
        float v = 0.0f;
        if (c < 2 * FB) {
            int f = c >> 1;
            const float* bb = (c & 1) ? b2i : b2r;
#pragma unroll
            for (int ee = 0; ee < NE; ee++) v += sg[ee] * bb[ee * FB + f];
            float cf = (f == 0 || f == FB - 1) ? 1.0f : 2.0f;
            v *= cf * (1.0f / (float)NN);
        }
        biasCs[b * BIAS_LD + c] = v;
    }
}

// ---------------------------------------------------------------------------
// biasT[b][t] = sum_c biasCs[b][c]*Ffwd[c][t]. Grid (16, BATCH), 512 blocks.
// ---------------------------------------------------------------------------
__global__ void biasT_kernel(const float* __restrict__ biasCs, const bf16* __restrict__ Ffwd,
                             float* __restrict__ biasT) {
    __shared__ float red[256];
    int b = blockIdx.y;
    int t = blockIdx.x * 64 + (threadIdx.x & 63);
    int part = threadIdx.x >> 6;       // 0..3
    float s = 0.0f;
    for (int c = part; c < 2 * FB; c += 4)
        s += biasCs[b * BIAS_LD + c] * __bfloat162float(Ffwd[(size_t)c * NN + t]);
    red[threadIdx.x] = s;
    __syncthreads();
    if (threadIdx.x < 64) {
        float v = red[threadIdx.x] + red[threadIdx.x + 64] +
                  red[threadIdx.x + 128] + red[threadIdx.x + 192];
        biasT[b * NN + t] = v;
    }
}

// ---------------------------------------------------------------------------
// out[r][t] = sum_z bf16plane_z[r][t] + biasT[r>>7][t]
// ---------------------------------------------------------------------------
__global__ void reduce_out4(const bf16* __restrict__ planes, const float* __restrict__ biasT,
                            float* __restrict__ out) {
    long idx = (long)blockIdx.x * 256 + threadIdx.x;
    if (idx >= (long)MR * NN / 8) return;
    size_t base = (size_t)idx * 8;
    long r = base >> 10;
    int t = (int)(base & (NN - 1));
    float s[8] = {};
#pragma unroll
    for (int z = 0; z < 4; z++) {
        short8 v = *(const short8*)(planes + (size_t)z * MR * NN + base);
#pragma unroll
        for (int j = 0; j < 8; j++) s[j] += bu2f((unsigned short)v[j]);
    }
    const float* bT = biasT + (r >> 7) * NN + t;
    float4 o0 = {s[0] + bT[0], s[1] + bT[1], s[2] + bT[2], s[3] + bT[3]};
    float4 o1 = {s[4] + bT[4], s[5] + bT[5], s[6] + bT[6], s[7] + bT[7]};
    *(float4*)(out + base) = o0;
    *(float4*)(out + base + 4) = o1;
}

// ---------------------------------------------------------------------------
// 128^2 MFMA GEMM (L1 only): EPI1 = relu(acc+bias)*gate -> bf16, per-z expert
// ---------------------------------------------------------------------------
template <int EPI>
__global__ void gemm_mfma(const bf16* __restrict__ A, int lda,
                          const bf16* __restrict__ B, int ldb, size_t zBstride,
                          void* __restrict__ Cv, int ldc, size_t zCoff,
                          int N, int K, int kPerZ,
                          const int* __restrict__ se2,
                          const float* __restrict__ biasR, const float* __restrict__ biasI,
                          int zBias, const float* __restrict__ gate8) {
    __shared__ bf16 As[128 * 32];
    __shared__ bf16 Bs[128 * 32];
    int tid = threadIdx.x;
    int zz = blockIdx.z;
    int bx, by;
    xcd_swizzle(&bx, &by);
    int row0 = by * 128, col0 = bx * 128;
    const bf16* Bz = B + (size_t)zz * zBstride;

    int kS, kE;
    if (EPI == 1) { int s = se2[2 * zz], e = se2[2 * zz + 1]; kS = (2 * s) & ~31; kE = (2 * e + 31) & ~31; }
    else          { kS = zz * kPerZ; kE = min(K, kS + kPerZ); }

    f32x4 acc[4][4] = {};

    int lane = tid & 63, wid = tid >> 6;
    int wrB = (wid >> 1) << 6, wcB = (wid & 1) << 6;
    int lr = lane & 15, lk = (lane >> 4) << 3;

    int r_a = tid >> 2, c_a = (tid & 3) << 3;
    int r_b = (tid + 256) >> 2, c_b = ((tid + 256) & 3) << 3;

    for (int kt = kS; kt < kE; kt += 32) {
        gload16(A + (size_t)(row0 + r_a) * lda + kt + c_a, &As[(size_t)tid * 8]);
        gload16(A + (size_t)(row0 + r_b) * lda + kt + c_b, &As[((size_t)tid + 256) * 8]);
        gload16(Bz + (size_t)(col0 + r_a) * ldb + kt + c_a, &Bs[(size_t)tid * 8]);
        gload16(Bz + (size_t)(col0 + r_b) * ldb + kt + c_b, &Bs[((size_t)tid + 256) * 8]);
        __syncthreads();
        short8 av[4], bv[4];
#pragma unroll
        for (int m = 0; m < 4; m++)
            av[m] = *(const short8*)&As[(wrB + m * 16 + lr) * 32 + lk];
#pragma unroll
        for (int n = 0; n < 4; n++)
            bv[n] = *(const short8*)&Bs[(wcB + n * 16 + lr) * 32 + lk];
#pragma unroll
        for (int m = 0; m < 4; m++)
#pragma unroll
            for (int n = 0; n < 4; n++)
                acc[m][n] = __builtin_amdgcn_mfma_f32_16x16x32_bf16(av[m], bv[n], acc[m][n], 0, 0, 0);
        __syncthreads();
    }

    int r0 = row0 + wrB + ((lane >> 4) << 2);
    int c0i = col0 + wcB + (lane & 15);
    float g = (EPI == 1) ? gate8[(row0 >> 7) * NE + zz] : 0.0f;

#pragma unroll
    for (int m = 0; m < 4; m++)
#pragma unroll
        for (int n = 0; n < 4; n++) {
            int c = c0i + n * 16;
            if (c >= N) continue;
#pragma unroll
            for (int j = 0; j < 4; j++) {
                int r = r0 + m * 16 + j;
                float v = acc[m][n][j];
                if (EPI == 1) {
                    v += (c < HD) ? biasR[zz * zBias + c] : biasI[zz * zBias + c - HD];
                    v = fmaxf(v, 0.0f) * g;
                    ((bf16*)Cv + (size_t)zz * zCoff)[(size_t)r * ldc + c] = f2b(v);
                } else {
                    ((float*)Cv + (size_t)zz * zCoff)[(size_t)r * ldc + c] = v;
                }
            }
        }
}

// ---------------------------------------------------------------------------
// 8-phase 256x256 GEMM body — R10-proven schedule (best measured: 125-126 us):
// A-halves staged at iter top + counted vmcnt(4); B-halves staged after
// CLUST(0) under compute; A-frag ds_reads pipelined one phase ahead.
// ---------------------------------------------------------------------------
__device__ __forceinline__ void stage_half(const bf16* gbase, int ld, int kt,
                                           bf16* ldsBase, int tid) {
#pragma unroll
    for (int j = 0; j < 2; j++) {
        int r = j * 64 + (tid >> 3);
        int sc = ((tid & 7) ^ ((tid >> 3) & 7)) * 8;
        gload16(gbase + (size_t)r * ld + kt + sc, ldsBase + j * 4096 + tid * 8);
    }
}

#define MF(a, b, c) __builtin_amdgcn_mfma_f32_16x16x32_bf16(a, b, c, 0, 0, 0)
#define RD(off) (*(const short8*)(bc + (off)))
#define LOADA(dst, FM)                                                        \
    dst[0] = RD(aBase + (FM) * 1024 + cb0);                                   \
    dst[1] = RD(aBase + (FM) * 1024 + cb1);                                   \
    dst[2] = RD(aBase + (FM + 1) * 1024 + cb0);                               \
    dst[3] = RD(aBase + (FM + 1) * 1024 + cb1);
#define CLUST(FM, av)                                                         \
    __builtin_amdgcn_s_setprio(1);                                            \
    acc[FM][0] = MF(av[0], b0[0], acc[FM][0]);                                \
    acc[FM][0] = MF(av[1], b1[0], acc[FM][0]);                                \
    acc[FM][1] = MF(av[0], b0[1], acc[FM][1]);                                \
    acc[FM][1] = MF(av[1], b1[1], acc[FM][1]);                                \
    acc[FM][2] = MF(av[0], b0[2], acc[FM][2]);                                \
    acc[FM][2] = MF(av[1], b1[2], acc[FM][2]);                                \
    acc[FM][3] = MF(av[0], b0[3], acc[FM][3]);                                \
    acc[FM][3] = MF(av[1], b1[3], acc[FM][3]);                                \
    acc[FM + 1][0] = MF(av[2], b0[0], acc[FM + 1][0]);                        \
    acc[FM + 1][0] = MF(av[3], b1[0], acc[FM + 1][0]);                        \
    acc[FM + 1][1] = MF(av[2], b0[1], acc[FM + 1][1]);                        \
    acc[FM + 1][1] = MF(av[3], b1[1], acc[FM + 1][1]);                        \
    acc[FM + 1][2] = MF(av[2], b0[2], acc[FM + 1][2]);                        \
    acc[FM + 1][2] = MF(av[3], b1[2], acc[FM + 1][2]);                        \
    acc[FM + 1][3] = MF(av[2], b0[3], acc[FM + 1][3]);                        \
    acc[FM + 1][3] = MF(av[3], b1[3], acc[FM + 1][3]);                        \
    __builtin_amdgcn_s_setprio(0);
#define PBAR { __builtin_amdgcn_sched_barrier(0); __builtin_amdgcn_s_barrier(); }

__device__ __forceinline__ void gemm8p_body(
        bf16* sm, const bf16* __restrict__ A, int lda,
        const bf16* __restrict__ B, int ldb,
        bf16* __restrict__ C, int ldc,
        int row0, int col0, int kS, int nt) {
    int tid = threadIdx.x;
    const bf16* Ab = A + (size_t)row0 * lda;
    const bf16* Bb = B + (size_t)col0 * ldb;

    // prologue: stage tile 0 into buf0
    stage_half(Ab, lda, kS, sm, tid);
    stage_half(Ab + (size_t)128 * lda, lda, kS, sm + 8192, tid);
    stage_half(Bb, ldb, kS, sm + 16384, tid);
    stage_half(Bb + (size_t)128 * ldb, ldb, kS, sm + 24576, tid);

    f32x4 acc[8][4] = {};

    int l = tid & 63, w = tid >> 6;
    int wm = w >> 2, wn = w & 3;
    int lr = l & 15, lk4 = l >> 4;
    int swz = lr & 7;
    int cb0 = ((lk4) ^ swz) * 8;
    int cb1 = ((4 + lk4) ^ swz) * 8;
    int aBase = wm * 8192 + lr * 64;
    int bBase = 16384 + (wn >> 1) * 8192 + (wn & 1) * 4096 + lr * 64;

    for (int t = 0; t < nt; ++t) {
        const bf16* bc = sm + (t & 1) * 32768;
        bf16* bufN = sm + ((t & 1) ^ 1) * 32768;
        int ktn = kS + (t + 1) * 64;
        bool more = (t + 1) < nt;
        // tile boundary: stage A halves of t+1, counted vmcnt, barrier
        if (more) {
            stage_half(Ab, lda, ktn, bufN, tid);
            stage_half(Ab + (size_t)128 * lda, lda, ktn, bufN + 8192, tid);
            asm volatile("s_waitcnt vmcnt(4)" ::: "memory");
        } else {
            asm volatile("s_waitcnt vmcnt(0)" ::: "memory");
        }
        __builtin_amdgcn_s_barrier();
        __builtin_amdgcn_sched_barrier(0);
        short8 b0[4], b1[4], a0[4], a1[4], a2[4], a3[4];
#pragma unroll
        for (int n = 0; n < 4; n++) {
            b0[n] = RD(bBase + n * 1024 + cb0);
            b1[n] = RD(bBase + n * 1024 + cb1);
        }
        LOADA(a0, 0)
        LOADA(a1, 2)
        __builtin_amdgcn_sched_barrier(0);
        CLUST(0, a0)
        if (more) {                  // stage B halves of t+1 under compute
            stage_half(Bb, ldb, ktn, bufN + 16384, tid);
            stage_half(Bb + (size_t)128 * ldb, ldb, ktn, bufN + 24576, tid);
        }
        LOADA(a2, 4)
        PBAR
        CLUST(2, a1)
        LOADA(a3, 6)
        PBAR
        CLUST(4, a2)
        PBAR
        CLUST(6, a3)
        PBAR
    }

    // epilogue: bf16 store, exact dims
    int rb = row0 + wm * 128 + lk4 * 4;
    int cbase = col0 + wn * 64 + lr;
#pragma unroll
    for (int fm = 0; fm < 8; fm++)
#pragma unroll
        for (int n = 0; n < 4; n++)
#pragma unroll
            for (int j = 0; j < 4; j++)
                C[(size_t)(rb + fm * 16 + j) * ldc + cbase + n * 16] = f2b(acc[fm][n][j]);
}

// combo: blocks [0,nb0) run job0 (B2inv), [nb0,total) run job1 (DFT).
__global__ __launch_bounds__(512, 2) void gemm8p_combo(
        const bf16* A0, int lda0, const bf16* B0, int ldb0, bf16* C0, int ldc0,
        int gx0, int nt0, int nb0,
        const bf16* A1, int lda1, const bf16* B1w, int ldb1, bf16* C1, int ldc1,
        int gx1, int nt1) {
    __shared__ bf16 sm[65536];
    int id = blockIdx.x;
    bool p0 = id < nb0;
    const bf16* A = p0 ? A0 : A1; int lda = p0 ? lda0 : lda1;
    const bf16* B = p0 ? B0 : B1w; int ldb = p0 ? ldb0 : ldb1;
    bf16* C = p0 ? C0 : C1; int ldc = p0 ? ldc0 : ldc1;
    int gx = p0 ? gx0 : gx1, nt = p0 ? nt0 : nt1;
    int id2 = p0 ? id : id - nb0;
    int bx = id2 % gx, by = id2 / gx;
    gemm8p_body(sm, A, lda, B, ldb, C, ldc, by * 256, bx * 256, 0, nt);
}

// L2: 256 blocks, XCD-bijective (4x,16y,4z) mapping, z slices K.
__global__ __launch_bounds__(512, 2) void gemm8p_l2(
        const bf16* __restrict__ A, int lda, const bf16* __restrict__ B, int ldb,
        bf16* __restrict__ C, int ldc, size_t zCoff, int tilesPerZ) {
    __shared__ bf16 sm[65536];
    int id = blockIdx.x;
    int by_z = (id & 7) * 8 + (id >> 5);
    int bx = (id >> 3) & 3;
    int z = by_z >> 4;
    int by = by_z & 15;
    gemm8p_body(sm, A, lda, B, ldb, C + (size_t)z * zCoff, ldc,
                by * 256, bx * 256, z * tilesPerZ * 64, tilesPerZ);
}

// ---------------------------------------------------------------------------
extern "C" void kernel_launch(void* const* d_in, const int* in_sizes, int n_in,
                              void* d_out, int out_size, void* d_ws, size_t ws_size,
                              hipStream_t stream) {
    const float* X   = (const float*)d_in[0];
    const float* bp  = (const float*)d_in[1];
    const float* W1r = (const float*)d_in[2];
    const float* W1i = (const float*)d_in[3];
    const float* b1r = (const float*)d_in[4];
    const float* b1i = (const float*)d_in[5];
    const float* W2r = (const float*)d_in[6];
    const float* W2i = (const float*)d_in[7];
    const float* b2r = (const float*)d_in[8];
    const float* b2i = (const float*)d_in[9];
    const float* gW  = (const float*)d_in[10];
    const float* gb  = (const float*)d_in[11];
    float* out = (float*)d_out;

    const size_t SZH = (size_t)MR * HP_LD * 2;   // 136.3 MB total for Hp

    // ---- carve workspace (~267.5 MB; proven budget from R6)
    char* p = (char*)d_ws;
    auto alloc = [&](size_t bytes) -> char* {
        char* r = p; p += (bytes + 255) & ~255ULL; return r;
    };
    int*   se     = (int*)alloc(64 * 4);
    float* magp   = (float*)alloc((size_t)BATCH * 8 * MAG_LD * 4);
    float* gate   = (float*)alloc((size_t)BATCH * NE * 4);
    float* biasCs = (float*)alloc((size_t)BATCH * BIAS_LD * 4);
    float* biasT  = (float*)alloc((size_t)BATCH * NN * 4);
    bf16*  Ffwd   = (bf16*)alloc((size_t)FF_ROWS * NN * 2);
    bf16*  Finv   = (bf16*)alloc((size_t)NN * FINV_LD * 2);
    // B1 slot (44.6 MB): B1 through L1, then L2 output planes (33.6 MB)
    char*  b1slot = alloc((size_t)NE * B1_ROWS * XINT_LD * 2);
    bf16*  B1     = (bf16*)b1slot;
    bf16*  planesB = (bf16*)b1slot;
    bf16*  B2t    = (bf16*)alloc((size_t)KCAT * FINV_LD * 2);
    bf16*  Xint   = (bf16*)alloc((size_t)MR * XINT_LD * 2);
    bf16*  B2inv  = (bf16*)alloc((size_t)NN * KCAT * 2);       // own slot (34.1 MB)
    bf16*  Hp     = (bf16*)alloc(8 * SZH);
    bf16*  Xb     = (bf16*)((char*)Hp + 8 * SZH - (size_t)MR * NN * 2);  // Hp tail

    // ---- prep (split: LDS-free bulk at full occupancy; LDS transpose separate)
    prep_kernel<<<1, 64, 0, stream>>>(bp, se);
    prep_bulk<<<(unsigned)((N_PREP + 255) / 256), 256, 0, stream>>>(
        W1r, W1i, X, se, Ffwd, Finv, B1, Xb);
    pack_B2t<<<dim3(9, 17, 8), 256, 0, stream>>>(W2r, W2i, B2t);

    // ---- combo: B2inv[1024][16640] = Finv * B2t^T (260 blocks)
    //           ∥ DFT: Xint[4096][1280] = Xb * Ffwd^T  (80 blocks)
    gemm8p_combo<<<340, 512, 0, stream>>>(
        Finv, FINV_LD, B2t, FINV_LD, B2inv, KCAT, 65, 17, 260,
        Xb, NN, Ffwd, NN, Xint, XINT_LD, 5, 16);

    // ---- gate path (mag partials -> gate+biasCs -> biasT)
    mag_kernel<<<dim3(BATCH, 8), 256, 0, stream>>>(Xint, magp);
    gate_bias_kernel<<<BATCH, 256, 0, stream>>>(magp, gW, gb, b2r, b2i, gate, biasCs);
    biasT_kernel<<<dim3(16, BATCH), 256, 0, stream>>>(biasCs, Ffwd, biasT);

    // ---- L1 (all 8 experts, gate folded): Hp[4096][16640]  (B1 still intact)
    gemm_mfma<1><<<dim3(17, 32, 8), 256, 0, stream>>>(
        Xint, XINT_LD, B1, XINT_LD, (size_t)B1_ROWS * XINT_LD,
        Hp, KCAT, HP_LD, 2 * HD, 0, 0,
        se, b1r, b1i, HD, gate);

    // ---- L2+iDFT fused: plane_z = Hp * B2inv^T over z's K-slice
    //      (planes live in B1's slot — B1 dead after L1)
    gemm8p_l2<<<256, 512, 0, stream>>>(
        Hp, KCAT, B2inv, KCAT, planesB, NN, (size_t)MR * NN, 65);

    // ---- reduce 4 planes + biasT -> out
    reduce_out4<<<(unsigned)(((size_t)MR * NN / 8 + 255) / 256), 256, 0, stream>>>(
        planesB, biasT, out);
}

// Round 16
// 395.351 us; speedup vs baseline: 1.0960x; 1.0013x over previous
//
#include <hip/hip_runtime.h>
#include <hip/hip_bf16.h>
#include <math.h>

typedef __hip_bfloat16 bf16;
typedef __attribute__((ext_vector_type(8))) short short8;
typedef __attribute__((ext_vector_type(4))) float f32x4;

#define FB 513
#define HD 1026
#define NN 1024
#define MR 4096      // 32*128 rows
#define NE 8
#define BATCH 32

#define XINT_LD 1280   // 2*FB padded to 5*256 (DFT gemm8p N)
#define BIAS_LD 1056
#define FINV_LD 1088   // 17*64 (Finv / B2t K-stride)
#define HP_LD   2080   // per-expert window in H'
#define B1_ROWS 2176
#define KCAT    16640  // 8*2080
#define MAG_LD  520
#define FF_ROWS 1280

__device__ __forceinline__ void gload16(const void* g, void* l) {
    __builtin_amdgcn_global_load_lds((const __attribute__((address_space(1))) void*)g,
                                     (__attribute__((address_space(3))) void*)l, 16, 0, 0);
}
__device__ __forceinline__ bf16 f2b(float v) { return __float2bfloat16(v); }
__device__ __forceinline__ unsigned short f2bu(float v) {
    bf16 b = __float2bfloat16(v);
    return *reinterpret_cast<unsigned short*>(&b);
}
__device__ __forceinline__ float bu2f(unsigned short u) {
    return __uint_as_float(((unsigned)u) << 16);
}
__device__ __forceinline__ unsigned pack2(float a, float b) {
    return (unsigned)f2bu(a) | ((unsigned)f2bu(b) << 16);
}

// ---------------------------------------------------------------------------
// prep_kernel: grid 4 x 256. Fills sctab[1024] = {cos, sin}(2*pi*k/1024);
// block 0 thread 0 additionally computes expert bin bounds.
// ---------------------------------------------------------------------------
__global__ void prep_kernel(const float* __restrict__ bp, int* __restrict__ se,
                            float2* __restrict__ sctab) {
    int k = blockIdx.x * 256 + threadIdx.x;
    const float TWO_PI = 6.283185307179586f;
    float s, c;
    sincosf(TWO_PI * (float)k / (float)NN, &s, &c);
    sctab[k] = make_float2(c, s);
    if (threadIdx.x == 0 && blockIdx.x == 0) {
        float b[9];
        b[0] = 0.0f; b[8] = 1.0f;
        for (int i = 0; i < 7; i++) b[i + 1] = 1.0f / (1.0f + expf(-bp[i]));
        for (int i = 1; i < 9; i++) { float v = b[i]; int j = i - 1;
            while (j >= 0 && b[j] > v) { b[j + 1] = b[j]; j--; } b[j + 1] = v; }
        int idx[9];
        for (int i = 0; i < 9; i++) idx[i] = (int)(b[i] * (float)(FB - 1));
        for (int e = 0; e < NE; e++) {
            se[2 * e] = idx[e];
            se[2 * e + 1] = (e < NE - 1) ? idx[e + 1] : FB;
        }
    }
}

// ---------------------------------------------------------------------------
// prep_bulk (NO LDS -> full occupancy): [Ffwd | Finv | B1 pairs | X pairs]
// Twiddles via sctab (8KB, L1/L2-resident) instead of per-thread sincosf.
// ---------------------------------------------------------------------------
#define N_FF  ((long)FF_ROWS * NN)                // 1,310,720
#define N_FI  (1024L * FINV_LD)                   // 1,114,112
#define N_B1P ((long)NE * B1_ROWS * (XINT_LD / 2))// 11,141,120
#define N_XP  ((long)MR * NN / 2)                 // 2,097,152
#define N_PREP (N_FF + N_FI + N_B1P + N_XP)       // 15,663,104

__global__ void prep_bulk(const float* __restrict__ W1r, const float* __restrict__ W1i,
                          const float* __restrict__ X, const int* __restrict__ se,
                          const float2* __restrict__ sctab,
                          bf16* __restrict__ Ffwd, bf16* __restrict__ Finv,
                          bf16* __restrict__ B1, bf16* __restrict__ Xb) {
    long i = (long)blockIdx.x * 256 + threadIdx.x;
    if (i < N_FF) {                 // Ffwd: rows 2f=cos, 2f+1=-sin; rows>=1026 zero
        int n = (int)(i >> 10), t = (int)(i & (NN - 1));
        float v = 0.0f;
        if (n < 2 * FB) {
            int f = n >> 1, k = (f * t) & (NN - 1);
            float2 sc = sctab[k];
            v = (n & 1) ? -sc.y : sc.x;
        }
        Ffwd[i] = f2b(v);
        return;
    }
    i -= N_FF;
    if (i < N_FI) {                 // Finv[1024][1088]
        int t = (int)(i / FINV_LD), k = (int)(i % FINV_LD);
        float v = 0.0f;
        if (k < 2 * FB) {
            int f = k >> 1, kk = (f * t) & (NN - 1);
            float2 sc = sctab[kk];
            float cf = (f == 0 || f == FB - 1) ? 1.0f : 2.0f;
            float scale = cf * (1.0f / (float)NN);
            v = (k & 1) ? -sc.y * scale : sc.x * scale;
        }
        Finv[i] = f2b(v);
        return;
    }
    i -= N_FI;
    if (i < N_B1P) {                // B1[e][2176][1280], pair (2f,2f+1)/thread
        int f = (int)(i % (XINT_LD / 2));
        long t = i / (XINT_LD / 2);
        int n = (int)(t % B1_ROWS);
        int e = (int)(t / B1_ROWS);
        float ve = 0.0f, vo = 0.0f;
        if (n < 2 * HD && f < FB && f >= se[2 * e] && f < se[2 * e + 1]) {
            int hi_part = (n >= HD);
            int h = hi_part ? n - HD : n;
            long wi = ((long)e * HD + h) * FB + f;
            float wr = W1r[wi], wim = W1i[wi];
            ve = hi_part ? wim : wr;
            vo = hi_part ? wr : -wim;
        }
        *(unsigned*)(B1 + ((size_t)(e * B1_ROWS + n)) * XINT_LD + 2 * f) = pack2(ve, vo);
        return;
    }
    i -= N_B1P;
    if (i < N_XP) {                 // X fp32 -> bf16, paired
        float2 v = ((const float2*)X)[i];
        *(unsigned*)(Xb + 2 * i) = pack2(v.x, v.y);
    }
}

// ---------------------------------------------------------------------------
// B2t[16640 k][1088 c] via LDS-tiled transpose (coalesced read AND write).
// ---------------------------------------------------------------------------
__global__ void pack_B2t(const float* __restrict__ W2r, const float* __restrict__ W2i,
                         bf16* __restrict__ B2t) {
    __shared__ float sR[64][65], sI[64][65];
    int e = blockIdx.z;
    int f0 = blockIdx.x * 64;
    int h0 = blockIdx.y * 64;
    int tid = threadIdx.x;
#pragma unroll
    for (int rep = 0; rep < 16; rep++) {
        int idx = tid + rep * 256;
        int fl = idx >> 6, hl = idx & 63;
        int f = f0 + fl, h = h0 + hl;
        bool ok = (f < FB) && (h < HD);
        size_t wi = ((size_t)e * FB + f) * HD + h;
        sR[fl][hl] = ok ? W2r[wi] : 0.0f;
        sI[fl][hl] = ok ? W2i[wi] : 0.0f;
    }
    __syncthreads();
#pragma unroll
    for (int rep = 0; rep < 4; rep++) {
        int idx = tid + rep * 256;        // 64 rows x 16 chunks of 8 bf16
        int hl = idx >> 4, ch = idx & 15;
        int h = h0 + hl;
        int c0 = 2 * f0 + ch * 8;
        if (c0 >= FINV_LD) continue;
        short8 lo, hi;
#pragma unroll
        for (int j = 0; j < 4; j++) {
            int fl = ch * 4 + j;
            float wr = sR[fl][hl], wim = sI[fl][hl];
            lo[2 * j]     = (short)f2bu(wr);
            lo[2 * j + 1] = (short)f2bu(wim);
            hi[2 * j]     = (short)f2bu(-wim);
            hi[2 * j + 1] = (short)f2bu(wr);
        }
        if (h < HD) {
            *(short8*)(B2t + ((size_t)e * HP_LD + h) * FINV_LD + c0) = lo;
            *(short8*)(B2t + ((size_t)e * HP_LD + HD + h) * FINV_LD + c0) = hi;
        } else if (HD + h < HP_LD) {
            short8 z = {};
            *(short8*)(B2t + ((size_t)e * HP_LD + HD + h) * FINV_LD + c0) = z;
        }
    }
}

// ---------------------------------------------------------------------------
__global__ void mag_kernel(const bf16* __restrict__ Xint, float* __restrict__ magp) {
    int b = blockIdx.x, g = blockIdx.y, t = threadIdx.x;
    float acc[3] = {0.0f, 0.0f, 0.0f};
    const bf16* base = Xint + ((size_t)b * 128 + g * 16) * XINT_LD;
    for (int c = 0; c < 16; c++) {
        const bf16* row = base + (size_t)c * XINT_LD;
#pragma unroll
        for (int kk = 0; kk < 3; kk++) {
            int f = t + 256 * kk;
            if (f < FB) {
                float xr = __bfloat162float(row[2 * f]);
                float xi = __bfloat162float(row[2 * f + 1]);
                acc[kk] += sqrtf(xr * xr + xi * xi);
            }
        }
    }
#pragma unroll
    for (int kk = 0; kk < 3; kk++) {
        int f = t + 256 * kk;
        if (f < FB) magp[((size_t)b * 8 + g) * MAG_LD + f] = acc[kk];
    }
}

// ---------------------------------------------------------------------------
// gate + scaled gated-bias: biasCs[b][c] = (c_f/N)*sum_e g_e*b2[e][f]
// ---------------------------------------------------------------------------
__global__ void gate_bias_kernel(const float* __restrict__ magp, const float* __restrict__ gW,
                                 const float* __restrict__ gb, const float* __restrict__ b2r,
                                 const float* __restrict__ b2i, float* __restrict__ gate,
                                 float* __restrict__ biasCs) {
    __shared__ float sred[256];
    __shared__ float sg[8];
    int b = blockIdx.x, tid = threadIdx.x;
    int e = tid & 7, j = tid >> 3;
    float acc = 0.0f;
    for (int f = j; f < FB; f += 32) {
        float m = 0.0f;
#pragma unroll
        for (int g = 0; g < 8; g++) m += magp[((size_t)b * 8 + g) * MAG_LD + f];
        acc += m * (1.0f / 128.0f) * gW[e * FB + f];
    }
    sred[tid] = acc;
    __syncthreads();
    if (tid < 64) {
        float a = sred[tid] + sred[tid + 64] + sred[tid + 128] + sred[tid + 192];
        a += __shfl_xor(a, 8); a += __shfl_xor(a, 16); a += __shfl_xor(a, 32);
        float logit = a + gb[e];
        float mx = logit;
        mx = fmaxf(mx, __shfl_xor(mx, 1)); mx = fmaxf(mx, __shfl_xor(mx, 2)); mx = fmaxf(mx, __shfl_xor(mx, 4));
        float ex = expf(logit - mx);
        float sum = ex;
        sum += __shfl_xor(sum, 1); sum += __shfl_xor(sum, 2); sum += __shfl_xor(sum, 4);
        if (tid < 8) { float g_ = ex / sum; sg[tid] = g_; gate[b * NE + tid] = g_; }
    }
    __syncthreads();
    for (int c = tid; c < BIAS_LD; c += 256) {
        float v = 0.0f;
        if (c < 2 * FB) {
            int f = c >> 1;
            const float* bb = (c & 1) ? b2i : b2r;
#pragma unroll
            for (int ee = 0; ee < NE; ee++) v += sg[ee] * bb[ee * FB + f];
            float cf = (f == 0 || f == FB - 1) ? 1.0f : 2.0f;
            v *= cf * (1.0f / (float)NN);
        }
        biasCs[b * BIAS_LD + c] = v;
    }
}

// ---------------------------------------------------------------------------
// biasT[b][t] = sum_c biasCs[b][c]*Ffwd[c][t]. Grid (16, BATCH), 512 blocks.
// ---------------------------------------------------------------------------
__global__ void biasT_kernel(const float* __restrict__ biasCs, const bf16* __restrict__ Ffwd,
                             float* __restrict__ biasT) {
    __shared__ float red[256];
    int b = blockIdx.y;
    int t = blockIdx.x * 64 + (threadIdx.x & 63);
    int part = threadIdx.x >> 6;       // 0..3
    float s = 0.0f;
    for (int c = part; c < 2 * FB; c += 4)
        s += biasCs[b * BIAS_LD + c] * __bfloat162float(Ffwd[(size_t)c * NN + t]);
    red[threadIdx.x] = s;
    __syncthreads();
    if (threadIdx.x < 64) {
        float v = red[threadIdx.x] + red[threadIdx.x + 64] +
                  red[threadIdx.x + 128] + red[threadIdx.x + 192];
        biasT[b * NN + t] = v;
    }
}

// ---------------------------------------------------------------------------
// out[r][t] = sum_z bf16plane_z[r][t] + biasT[r>>7][t]
// ---------------------------------------------------------------------------
__global__ void reduce_out4(const bf16* __restrict__ planes, const float* __restrict__ biasT,
                            float* __restrict__ out) {
    long idx = (long)blockIdx.x * 256 + threadIdx.x;
    if (idx >= (long)MR * NN / 8) return;
    size_t base = (size_t)idx * 8;
    long r = base >> 10;
    int t = (int)(base & (NN - 1));
    float s[8] = {};
#pragma unroll
    for (int z = 0; z < 4; z++) {
        short8 v = *(const short8*)(planes + (size_t)z * MR * NN + base);
#pragma unroll
        for (int j = 0; j < 8; j++) s[j] += bu2f((unsigned short)v[j]);
    }
    const float* bT = biasT + (r >> 7) * NN + t;
    float4 o0 = {s[0] + bT[0], s[1] + bT[1], s[2] + bT[2], s[3] + bT[3]};
    float4 o1 = {s[4] + bT[4], s[5] + bT[5], s[6] + bT[6], s[7] + bT[7]};
    *(float4*)(out + base) = o0;
    *(float4*)(out + base + 4) = o1;
}

// ---------------------------------------------------------------------------
// 128^2 MFMA GEMM (L1 only): EPI1 = relu(acc+bias)*gate -> bf16, per-z expert
// ---------------------------------------------------------------------------
__device__ __forceinline__ void xcd_swizzle(int* px, int* py) {
    int gx = gridDim.x;
    int orig = blockIdx.x + gx * blockIdx.y;
    int q = (gx * gridDim.y) >> 3;
    int wg = (orig & 7) * q + (orig >> 3);
    *px = wg % gx;
    *py = wg / gx;
}

template <int EPI>
__global__ void gemm_mfma(const bf16* __restrict__ A, int lda,
                          const bf16* __restrict__ B, int ldb, size_t zBstride,
                          void* __restrict__ Cv, int ldc, size_t zCoff,
                          int N, int K, int kPerZ,
                          const int* __restrict__ se2,
                          const float* __restrict__ biasR, const float* __restrict__ biasI,
                          int zBias, const float* __restrict__ gate8) {
    __shared__ bf16 As[128 * 32];
    __shared__ bf16 Bs[128 * 32];
    int tid = threadIdx.x;
    int zz = blockIdx.z;
    int bx, by;
    xcd_swizzle(&bx, &by);
    int row0 = by * 128, col0 = bx * 128;
    const bf16* Bz = B + (size_t)zz * zBstride;

    int kS, kE;
    if (EPI == 1) { int s = se2[2 * zz], e = se2[2 * zz + 1]; kS = (2 * s) & ~31; kE = (2 * e + 31) & ~31; }
    else          { kS = zz * kPerZ; kE = min(K, kS + kPerZ); }

    f32x4 acc[4][4] = {};

    int lane = tid & 63, wid = tid >> 6;
    int wrB = (wid >> 1) << 6, wcB = (wid & 1) << 6;
    int lr = lane & 15, lk = (lane >> 4) << 3;

    int r_a = tid >> 2, c_a = (tid & 3) << 3;
    int r_b = (tid + 256) >> 2, c_b = ((tid + 256) & 3) << 3;

    for (int kt = kS; kt < kE; kt += 32) {
        gload16(A + (size_t)(row0 + r_a) * lda + kt + c_a, &As[(size_t)tid * 8]);
        gload16(A + (size_t)(row0 + r_b) * lda + kt + c_b, &As[((size_t)tid + 256) * 8]);
        gload16(Bz + (size_t)(col0 + r_a) * ldb + kt + c_a, &Bs[(size_t)tid * 8]);
        gload16(Bz + (size_t)(col0 + r_b) * ldb + kt + c_b, &Bs[((size_t)tid + 256) * 8]);
        __syncthreads();
        short8 av[4], bv[4];
#pragma unroll
        for (int m = 0; m < 4; m++)
            av[m] = *(const short8*)&As[(wrB + m * 16 + lr) * 32 + lk];
#pragma unroll
        for (int n = 0; n < 4; n++)
            bv[n] = *(const short8*)&Bs[(wcB + n * 16 + lr) * 32 + lk];
#pragma unroll
        for (int m = 0; m < 4; m++)
#pragma unroll
            for (int n = 0; n < 4; n++)
                acc[m][n] = __builtin_amdgcn_mfma_f32_16x16x32_bf16(av[m], bv[n], acc[m][n], 0, 0, 0);
        __syncthreads();
    }

    int r0 = row0 + wrB + ((lane >> 4) << 2);
    int c0i = col0 + wcB + (lane & 15);
    float g = (EPI == 1) ? gate8[(row0 >> 7) * NE + zz] : 0.0f;

#pragma unroll
    for (int m = 0; m < 4; m++)
#pragma unroll
        for (int n = 0; n < 4; n++) {
            int c = c0i + n * 16;
            if (c >= N) continue;
#pragma unroll
            for (int j = 0; j < 4; j++) {
                int r = r0 + m * 16 + j;
                float v = acc[m][n][j];
                if (EPI == 1) {
                    v += (c < HD) ? biasR[zz * zBias + c] : biasI[zz * zBias + c - HD];
                    v = fmaxf(v, 0.0f) * g;
                    ((bf16*)Cv + (size_t)zz * zCoff)[(size_t)r * ldc + c] = f2b(v);
                } else {
                    ((float*)Cv + (size_t)zz * zCoff)[(size_t)r * ldc + c] = v;
                }
            }
        }
}

// ---------------------------------------------------------------------------
// 8-phase 256x256 GEMM body — R10-proven schedule (best measured: 125-126 us).
// FROZEN: R9-R13 established this variant as the optimum of its family.
// ---------------------------------------------------------------------------
__device__ __forceinline__ void stage_half(const bf16* gbase, int ld, int kt,
                                           bf16* ldsBase, int tid) {
#pragma unroll
    for (int j = 0; j < 2; j++) {
        int r = j * 64 + (tid >> 3);
        int sc = ((tid & 7) ^ ((tid >> 3) & 7)) * 8;
        gload16(gbase + (size_t)r * ld + kt + sc, ldsBase + j * 4096 + tid * 8);
    }
}

#define MF(a, b, c) __builtin_amdgcn_mfma_f32_16x16x32_bf16(a, b, c, 0, 0, 0)
#define RD(off) (*(const short8*)(bc + (off)))
#define LOADA(dst, FM)                                                        \
    dst[0] = RD(aBase + (FM) * 1024 + cb0);                                   \
    dst[1] = RD(aBase + (FM) * 1024 + cb1);                                   \
    dst[2] = RD(aBase + (FM + 1) * 1024 + cb0);                               \
    dst[3] = RD(aBase + (FM + 1) * 1024 + cb1);
#define CLUST(FM, av)                                                         \
    __builtin_amdgcn_s_setprio(1);                                            \
    acc[FM][0] = MF(av[0], b0[0], acc[FM][0]);                                \
    acc[FM][0] = MF(av[1], b1[0], acc[FM][0]);                                \
    acc[FM][1] = MF(av[0], b0[1], acc[FM][1]);                                \
    acc[FM][1] = MF(av[1], b1[1], acc[FM][1]);                                \
    acc[FM][2] = MF(av[0], b0[2], acc[FM][2]);                                \
    acc[FM][2] = MF(av[1], b1[2], acc[FM][2]);                                \
    acc[FM][3] = MF(av[0], b0[3], acc[FM][3]);                                \
    acc[FM][3] = MF(av[1], b1[3], acc[FM][3]);                                \
    acc[FM + 1][0] = MF(av[2], b0[0], acc[FM + 1][0]);                        \
    acc[FM + 1][0] = MF(av[3], b1[0], acc[FM + 1][0]);                        \
    acc[FM + 1][1] = MF(av[2], b0[1], acc[FM + 1][1]);                        \
    acc[FM + 1][1] = MF(av[3], b1[1], acc[FM + 1][1]);                        \
    acc[FM + 1][2] = MF(av[2], b0[2], acc[FM + 1][2]);                        \
    acc[FM + 1][2] = MF(av[3], b1[2], acc[FM + 1][2]);                        \
    acc[FM + 1][3] = MF(av[2], b0[3], acc[FM + 1][3]);                        \
    acc[FM + 1][3] = MF(av[3], b1[3], acc[FM + 1][3]);                        \
    __builtin_amdgcn_s_setprio(0);
#define PBAR { __builtin_amdgcn_sched_barrier(0); __builtin_amdgcn_s_barrier(); }

__device__ __forceinline__ void gemm8p_body(
        bf16* sm, const bf16* __restrict__ A, int lda,
        const bf16* __restrict__ B, int ldb,
        bf16* __restrict__ C, int ldc,
        int row0, int col0, int kS, int nt) {
    int tid = threadIdx.x;
    const bf16* Ab = A + (size_t)row0 * lda;
    const bf16* Bb = B + (size_t)col0 * ldb;

    // prologue: stage tile 0 into buf0
    stage_half(Ab, lda, kS, sm, tid);
    stage_half(Ab + (size_t)128 * lda, lda, kS, sm + 8192, tid);
    stage_half(Bb, ldb, kS, sm + 16384, tid);
    stage_half(Bb + (size_t)128 * ldb, ldb, kS, sm + 24576, tid);

    f32x4 acc[8][4] = {};

    int l = tid & 63, w = tid >> 6;
    int wm = w >> 2, wn = w & 3;
    int lr = l & 15, lk4 = l >> 4;
    int swz = lr & 7;
    int cb0 = ((lk4) ^ swz) * 8;
    int cb1 = ((4 + lk4) ^ swz) * 8;
    int aBase = wm * 8192 + lr * 64;
    int bBase = 16384 + (wn >> 1) * 8192 + (wn & 1) * 4096 + lr * 64;

    for (int t = 0; t < nt; ++t) {
        const bf16* bc = sm + (t & 1) * 32768;
        bf16* bufN = sm + ((t & 1) ^ 1) * 32768;
        int ktn = kS + (t + 1) * 64;
        bool more = (t + 1) < nt;
        // tile boundary: stage A halves of t+1, counted vmcnt, barrier
        if (more) {
            stage_half(Ab, lda, ktn, bufN, tid);
            stage_half(Ab + (size_t)128 * lda, lda, ktn, bufN + 8192, tid);
            asm volatile("s_waitcnt vmcnt(4)" ::: "memory");
        } else {
            asm volatile("s_waitcnt vmcnt(0)" ::: "memory");
        }
        __builtin_amdgcn_s_barrier();
        __builtin_amdgcn_sched_barrier(0);
        short8 b0[4], b1[4], a0[4], a1[4], a2[4], a3[4];
#pragma unroll
        for (int n = 0; n < 4; n++) {
            b0[n] = RD(bBase + n * 1024 + cb0);
            b1[n] = RD(bBase + n * 1024 + cb1);
        }
        LOADA(a0, 0)
        LOADA(a1, 2)
        __builtin_amdgcn_sched_barrier(0);
        CLUST(0, a0)
        if (more) {                  // stage B halves of t+1 under compute
            stage_half(Bb, ldb, ktn, bufN + 16384, tid);
            stage_half(Bb + (size_t)128 * ldb, ldb, ktn, bufN + 24576, tid);
        }
        LOADA(a2, 4)
        PBAR
        CLUST(2, a1)
        LOADA(a3, 6)
        PBAR
        CLUST(4, a2)
        PBAR
        CLUST(6, a3)
        PBAR
    }

    // epilogue: bf16 store, exact dims
    int rb = row0 + wm * 128 + lk4 * 4;
    int cbase = col0 + wn * 64 + lr;
#pragma unroll
    for (int fm = 0; fm < 8; fm++)
#pragma unroll
        for (int n = 0; n < 4; n++)
#pragma unroll
            for (int j = 0; j < 4; j++)
                C[(size_t)(rb + fm * 16 + j) * ldc + cbase + n * 16] = f2b(acc[fm][n][j]);
}

// combo: blocks [0,nb0) run job0 (B2inv), [nb0,total) run job1 (DFT).
__global__ __launch_bounds__(512, 2) void gemm8p_combo(
        const bf16* A0, int lda0, const bf16* B0, int ldb0, bf16* C0, int ldc0,
        int gx0, int nt0, int nb0,
        const bf16* A1, int lda1, const bf16* B1w, int ldb1, bf16* C1, int ldc1,
        int gx1, int nt1) {
    __shared__ bf16 sm[65536];
    int id = blockIdx.x;
    bool p0 = id < nb0;
    const bf16* A = p0 ? A0 : A1; int lda = p0 ? lda0 : lda1;
    const bf16* B = p0 ? B0 : B1w; int ldb = p0 ? ldb0 : ldb1;
    bf16* C = p0 ? C0 : C1; int ldc = p0 ? ldc0 : ldc1;
    int gx = p0 ? gx0 : gx1, nt = p0 ? nt0 : nt1;
    int id2 = p0 ? id : id - nb0;
    int bx = id2 % gx, by = id2 / gx;
    gemm8p_body(sm, A, lda, B, ldb, C, ldc, by * 256, bx * 256, 0, nt);
}

// L2: 256 blocks, XCD-bijective (4x,16y,4z) mapping, z slices K.
__global__ __launch_bounds__(512, 2) void gemm8p_l2(
        const bf16* __restrict__ A, int lda, const bf16* __restrict__ B, int ldb,
        bf16* __restrict__ C, int ldc, size_t zCoff, int tilesPerZ) {
    __shared__ bf16 sm[65536];
    int id = blockIdx.x;
    int by_z = (id & 7) * 8 + (id >> 5);
    int bx = (id >> 3) & 3;
    int z = by_z >> 4;
    int by = by_z & 15;
    gemm8p_body(sm, A, lda, B, ldb, C + (size_t)z * zCoff, ldc,
                by * 256, bx * 256, z * tilesPerZ * 64, tilesPerZ);
}

// ---------------------------------------------------------------------------
extern "C" void kernel_launch(void* const* d_in, const int* in_sizes, int n_in,
                              void* d_out, int out_size, void* d_ws, size_t ws_size,
                              hipStream_t stream) {
    const float* X   = (const float*)d_in[0];
    const float* bp  = (const float*)d_in[1];
    const float* W1r = (const float*)d_in[2];
    const float* W1i = (const float*)d_in[3];
    const float* b1r = (const float*)d_in[4];
    const float* b1i = (const float*)d_in[5];
    const float* W2r = (const float*)d_in[6];
    const float* W2i = (const float*)d_in[7];
    const float* b2r = (const float*)d_in[8];
    const float* b2i = (const float*)d_in[9];
    const float* gW  = (const float*)d_in[10];
    const float* gb  = (const float*)d_in[11];
    float* out = (float*)d_out;

    const size_t SZH = (size_t)MR * HP_LD * 2;   // 136.3 MB total for Hp

    // ---- carve workspace (~267.5 MB; proven budget from R6)
    char* p = (char*)d_ws;
    auto alloc = [&](size_t bytes) -> char* {
        char* r = p; p += (bytes + 255) & ~255ULL; return r;
    };
    int*   se     = (int*)alloc(64 * 4);
    float2* sctab = (float2*)alloc(NN * sizeof(float2));
    float* magp   = (float*)alloc((size_t)BATCH * 8 * MAG_LD * 4);
    float* gate   = (float*)alloc((size_t)BATCH * NE * 4);
    float* biasCs = (float*)alloc((size_t)BATCH * BIAS_LD * 4);
    float* biasT  = (float*)alloc((size_t)BATCH * NN * 4);
    bf16*  Ffwd   = (bf16*)alloc((size_t)FF_ROWS * NN * 2);
    bf16*  Finv   = (bf16*)alloc((size_t)NN * FINV_LD * 2);
    // B1 slot (44.6 MB): B1 through L1, then L2 output planes (33.6 MB)
    char*  b1slot = alloc((size_t)NE * B1_ROWS * XINT_LD * 2);
    bf16*  B1     = (bf16*)b1slot;
    bf16*  planesB = (bf16*)b1slot;
    bf16*  B2t    = (bf16*)alloc((size_t)KCAT * FINV_LD * 2);
    bf16*  Xint   = (bf16*)alloc((size_t)MR * XINT_LD * 2);
    bf16*  B2inv  = (bf16*)alloc((size_t)NN * KCAT * 2);       // own slot (34.1 MB)
    bf16*  Hp     = (bf16*)alloc(8 * SZH);
    bf16*  Xb     = (bf16*)((char*)Hp + 8 * SZH - (size_t)MR * NN * 2);  // Hp tail

    // ---- prep (bounds + twiddle table, then LDS-free bulk, then transpose)
    prep_kernel<<<4, 256, 0, stream>>>(bp, se, sctab);
    prep_bulk<<<(unsigned)((N_PREP + 255) / 256), 256, 0, stream>>>(
        W1r, W1i, X, se, sctab, Ffwd, Finv, B1, Xb);
    pack_B2t<<<dim3(9, 17, 8), 256, 0, stream>>>(W2r, W2i, B2t);

    // ---- combo: B2inv[1024][16640] = Finv * B2t^T (260 blocks)
    //           ∥ DFT: Xint[4096][1280] = Xb * Ffwd^T  (80 blocks)
    gemm8p_combo<<<340, 512, 0, stream>>>(
        Finv, FINV_LD, B2t, FINV_LD, B2inv, KCAT, 65, 17, 260,
        Xb, NN, Ffwd, NN, Xint, XINT_LD, 5, 16);

    // ---- gate path (mag partials -> gate+biasCs -> biasT)
    mag_kernel<<<dim3(BATCH, 8), 256, 0, stream>>>(Xint, magp);
    gate_bias_kernel<<<BATCH, 256, 0, stream>>>(magp, gW, gb, b2r, b2i, gate, biasCs);
    biasT_kernel<<<dim3(16, BATCH), 256, 0, stream>>>(biasCs, Ffwd, biasT);

    // ---- L1 (all 8 experts, gate folded): Hp[4096][16640]  (B1 still intact)
    gemm_mfma<1><<<dim3(17, 32, 8), 256, 0, stream>>>(
        Xint, XINT_LD, B1, XINT_LD, (size_t)B1_ROWS * XINT_LD,
        Hp, KCAT, HP_LD, 2 * HD, 0, 0,
        se, b1r, b1i, HD, gate);

    // ---- L2+iDFT fused: plane_z = Hp * B2inv^T over z's K-slice
    //      (planes live in B1's slot — B1 dead after L1)
    gemm8p_l2<<<256, 512, 0, stream>>>(
        Hp, KCAT, B2inv, KCAT, planesB, NN, (size_t)MR * NN, 65);

    // ---- reduce 4 planes + biasT -> out
    reduce_out4<<<(unsigned)(((size_t)MR * NN / 8 + 255) / 256), 256, 0, stream>>>(
        planesB, biasT, out);
}

// Round 17
// 377.644 us; speedup vs baseline: 1.1474x; 1.0469x over previous
//
#include <hip/hip_runtime.h>
#include <hip/hip_bf16.h>
#include <math.h>

typedef __hip_bfloat16 bf16;
typedef __attribute__((ext_vector_type(8))) short short8;
typedef __attribute__((ext_vector_type(4))) float f32x4;

#define FB 513
#define HD 1026
#define NN 1024
#define MR 4096      // 32*128 rows
#define NE 8
#define BATCH 32

#define XINT_LD 1280   // 2*FB padded to 5*256 (DFT gemm8p N)
#define BIAS_LD 1056
#define FINV_LD 1088   // 17*64 (Finv / B2t K-stride)
#define HP_LD   2080   // per-expert window in H'
#define B1_ROWS 2176
#define KCAT    16640  // 8*2080
#define MAG_LD  520
#define FF_ROWS 1280

__device__ __forceinline__ void gload16(const void* g, void* l) {
    __builtin_amdgcn_global_load_lds((const __attribute__((address_space(1))) void*)g,
                                     (__attribute__((address_space(3))) void*)l, 16, 0, 0);
}
__device__ __forceinline__ bf16 f2b(float v) { return __float2bfloat16(v); }
__device__ __forceinline__ unsigned short f2bu(float v) {
    bf16 b = __float2bfloat16(v);
    return *reinterpret_cast<unsigned short*>(&b);
}
__device__ __forceinline__ float bu2f(unsigned short u) {
    return __uint_as_float(((unsigned)u) << 16);
}
__device__ __forceinline__ unsigned pack2(float a, float b) {
    return (unsigned)f2bu(a) | ((unsigned)f2bu(b) << 16);
}

// ---------------------------------------------------------------------------
// prep_kernel: grid 4 x 256. Fills sctab[1024] = {cos,sin}(2*pi*k/1024);
// block 0 thread 0 additionally computes expert bin bounds.
// ---------------------------------------------------------------------------
__global__ void prep_kernel(const float* __restrict__ bp, int* __restrict__ se,
                            float2* __restrict__ sctab) {
    int k = blockIdx.x * 256 + threadIdx.x;
    const float TWO_PI = 6.283185307179586f;
    float s, c;
    sincosf(TWO_PI * (float)k / (float)NN, &s, &c);
    sctab[k] = make_float2(c, s);
    if (threadIdx.x == 0 && blockIdx.x == 0) {
        float b[9];
        b[0] = 0.0f; b[8] = 1.0f;
        for (int i = 0; i < 7; i++) b[i + 1] = 1.0f / (1.0f + expf(-bp[i]));
        for (int i = 1; i < 9; i++) { float v = b[i]; int j = i - 1;
            while (j >= 0 && b[j] > v) { b[j + 1] = b[j]; j--; } b[j + 1] = v; }
        int idx[9];
        for (int i = 0; i < 9; i++) idx[i] = (int)(b[i] * (float)(FB - 1));
        for (int e = 0; e < NE; e++) {
            se[2 * e] = idx[e];
            se[2 * e + 1] = (e < NE - 1) ? idx[e + 1] : FB;
        }
    }
}

// ---------------------------------------------------------------------------
// prep_bulk (NO LDS -> full occupancy): [Ffwd | Finv | B1 pairs | X pairs]
// ---------------------------------------------------------------------------
#define N_FF  ((long)FF_ROWS * NN)                // 1,310,720
#define N_FI  (1024L * FINV_LD)                   // 1,114,112
#define N_B1P ((long)NE * B1_ROWS * (XINT_LD / 2))// 11,141,120
#define N_XP  ((long)MR * NN / 2)                 // 2,097,152
#define N_PREP (N_FF + N_FI + N_B1P + N_XP)       // 15,663,104

__global__ void prep_bulk(const float* __restrict__ W1r, const float* __restrict__ W1i,
                          const float* __restrict__ X, const int* __restrict__ se,
                          const float2* __restrict__ sctab,
                          bf16* __restrict__ Ffwd, bf16* __restrict__ Finv,
                          bf16* __restrict__ B1, bf16* __restrict__ Xb) {
    long i = (long)blockIdx.x * 256 + threadIdx.x;
    if (i < N_FF) {                 // Ffwd: rows 2f=cos, 2f+1=-sin; rows>=1026 zero
        int n = (int)(i >> 10), t = (int)(i & (NN - 1));
        float v = 0.0f;
        if (n < 2 * FB) {
            int f = n >> 1, k = (f * t) & (NN - 1);
            float2 sc = sctab[k];
            v = (n & 1) ? -sc.y : sc.x;
        }
        Ffwd[i] = f2b(v);
        return;
    }
    i -= N_FF;
    if (i < N_FI) {                 // Finv[1024][1088]
        int t = (int)(i / FINV_LD), k = (int)(i % FINV_LD);
        float v = 0.0f;
        if (k < 2 * FB) {
            int f = k >> 1, kk = (f * t) & (NN - 1);
            float2 sc = sctab[kk];
            float cf = (f == 0 || f == FB - 1) ? 1.0f : 2.0f;
            float scale = cf * (1.0f / (float)NN);
            v = (k & 1) ? -sc.y * scale : sc.x * scale;
        }
        Finv[i] = f2b(v);
        return;
    }
    i -= N_FI;
    if (i < N_B1P) {                // B1[e][2176][1280], pair (2f,2f+1)/thread
        int f = (int)(i % (XINT_LD / 2));
        long t = i / (XINT_LD / 2);
        int n = (int)(t % B1_ROWS);
        int e = (int)(t / B1_ROWS);
        float ve = 0.0f, vo = 0.0f;
        if (n < 2 * HD && f < FB && f >= se[2 * e] && f < se[2 * e + 1]) {
            int hi_part = (n >= HD);
            int h = hi_part ? n - HD : n;
            long wi = ((long)e * HD + h) * FB + f;
            float wr = W1r[wi], wim = W1i[wi];
            ve = hi_part ? wim : wr;
            vo = hi_part ? wr : -wim;
        }
        *(unsigned*)(B1 + ((size_t)(e * B1_ROWS + n)) * XINT_LD + 2 * f) = pack2(ve, vo);
        return;
    }
    i -= N_B1P;
    if (i < N_XP) {                 // X fp32 -> bf16, paired
        float2 v = ((const float2*)X)[i];
        *(unsigned*)(Xb + 2 * i) = pack2(v.x, v.y);
    }
}

// ---------------------------------------------------------------------------
// B2t[16640 k][1088 c] via LDS-tiled transpose (coalesced read AND write).
// ---------------------------------------------------------------------------
__global__ void pack_B2t(const float* __restrict__ W2r, const float* __restrict__ W2i,
                         bf16* __restrict__ B2t) {
    __shared__ float sR[64][65], sI[64][65];
    int e = blockIdx.z;
    int f0 = blockIdx.x * 64;
    int h0 = blockIdx.y * 64;
    int tid = threadIdx.x;
#pragma unroll
    for (int rep = 0; rep < 16; rep++) {
        int idx = tid + rep * 256;
        int fl = idx >> 6, hl = idx & 63;
        int f = f0 + fl, h = h0 + hl;
        bool ok = (f < FB) && (h < HD);
        size_t wi = ((size_t)e * FB + f) * HD + h;
        sR[fl][hl] = ok ? W2r[wi] : 0.0f;
        sI[fl][hl] = ok ? W2i[wi] : 0.0f;
    }
    __syncthreads();
#pragma unroll
    for (int rep = 0; rep < 4; rep++) {
        int idx = tid + rep * 256;        // 64 rows x 16 chunks of 8 bf16
        int hl = idx >> 4, ch = idx & 15;
        int h = h0 + hl;
        int c0 = 2 * f0 + ch * 8;
        if (c0 >= FINV_LD) continue;
        short8 lo, hi;
#pragma unroll
        for (int j = 0; j < 4; j++) {
            int fl = ch * 4 + j;
            float wr = sR[fl][hl], wim = sI[fl][hl];
            lo[2 * j]     = (short)f2bu(wr);
            lo[2 * j + 1] = (short)f2bu(wim);
            hi[2 * j]     = (short)f2bu(-wim);
            hi[2 * j + 1] = (short)f2bu(wr);
        }
        if (h < HD) {
            *(short8*)(B2t + ((size_t)e * HP_LD + h) * FINV_LD + c0) = lo;
            *(short8*)(B2t + ((size_t)e * HP_LD + HD + h) * FINV_LD + c0) = hi;
        } else if (HD + h < HP_LD) {
            short8 z = {};
            *(short8*)(B2t + ((size_t)e * HP_LD + HD + h) * FINV_LD + c0) = z;
        }
    }
}

// ---------------------------------------------------------------------------
__global__ void mag_kernel(const bf16* __restrict__ Xint, float* __restrict__ magp) {
    int b = blockIdx.x, g = blockIdx.y, t = threadIdx.x;
    float acc[3] = {0.0f, 0.0f, 0.0f};
    const bf16* base = Xint + ((size_t)b * 128 + g * 16) * XINT_LD;
    for (int c = 0; c < 16; c++) {
        const bf16* row = base + (size_t)c * XINT_LD;
#pragma unroll
        for (int kk = 0; kk < 3; kk++) {
            int f = t + 256 * kk;
            if (f < FB) {
                float xr = __bfloat162float(row[2 * f]);
                float xi = __bfloat162float(row[2 * f + 1]);
                acc[kk] += sqrtf(xr * xr + xi * xi);
            }
        }
    }
#pragma unroll
    for (int kk = 0; kk < 3; kk++) {
        int f = t + 256 * kk;
        if (f < FB) magp[((size_t)b * 8 + g) * MAG_LD + f] = acc[kk];
    }
}

// ---------------------------------------------------------------------------
// gate + scaled gated-bias: biasCs[b][c] = (c_f/N)*sum_e g_e*b2[e][f]
// ---------------------------------------------------------------------------
__global__ void gate_bias_kernel(const float* __restrict__ magp, const float* __restrict__ gW,
                                 const float* __restrict__ gb, const float* __restrict__ b2r,
                                 const float* __restrict__ b2i, float* __restrict__ gate,
                                 float* __restrict__ biasCs) {
    __shared__ float sred[256];
    __shared__ float sg[8];
    int b = blockIdx.x, tid = threadIdx.x;
    int e = tid & 7, j = tid >> 3;
    float acc = 0.0f;
    for (int f = j; f < FB; f += 32) {
        float m = 0.0f;
#pragma unroll
        for (int g = 0; g < 8; g++) m += magp[((size_t)b * 8 + g) * MAG_LD + f];
        acc += m * (1.0f / 128.0f) * gW[e * FB + f];
    }
    sred[tid] = acc;
    __syncthreads();
    if (tid < 64) {
        float a = sred[tid] + sred[tid + 64] + sred[tid + 128] + sred[tid + 192];
        a += __shfl_xor(a, 8); a += __shfl_xor(a, 16); a += __shfl_xor(a, 32);
        float logit = a + gb[e];
        float mx = logit;
        mx = fmaxf(mx, __shfl_xor(mx, 1)); mx = fmaxf(mx, __shfl_xor(mx, 2)); mx = fmaxf(mx, __shfl_xor(mx, 4));
        float ex = expf(logit - mx);
        float sum = ex;
        sum += __shfl_xor(sum, 1); sum += __shfl_xor(sum, 2); sum += __shfl_xor(sum, 4);
        if (tid < 8) { float g_ = ex / sum; sg[tid] = g_; gate[b * NE + tid] = g_; }
    }
    __syncthreads();
    for (int c = tid; c < BIAS_LD; c += 256) {
        float v = 0.0f;
        if (c < 2 * FB) {
            int f = c >> 1;
            const float* bb = (c & 1) ? b2i : b2r;
#pragma unroll
            for (int ee = 0; ee < NE; ee++) v += sg[ee] * bb[ee * FB + f];
            float cf = (f == 0 || f == FB - 1) ? 1.0f : 2.0f;
            v *= cf * (1.0f / (float)NN);
        }
        biasCs[b * BIAS_LD + c] = v;
    }
}

// ---------------------------------------------------------------------------
// biasT[b][t] = sum_c biasCs[b][c] * Ffwd[c][t]   (R10 form: grid (4, BATCH))
// ---------------------------------------------------------------------------
__global__ void biasT_kernel(const float* __restrict__ biasCs, const bf16* __restrict__ Ffwd,
                             float* __restrict__ biasT) {
    int t = blockIdx.x * 256 + threadIdx.x;
    int b = blockIdx.y;
    float s = 0.0f;
    for (int c = 0; c < 2 * FB; c++)
        s += biasCs[b * BIAS_LD + c] * __bfloat162float(Ffwd[(size_t)c * NN + t]);
    biasT[b * NN + t] = s;
}

// ---------------------------------------------------------------------------
// out[r][t] = sum_z bf16plane_z[r][t] + biasT[r>>7][t]
// ---------------------------------------------------------------------------
__global__ void reduce_out4(const bf16* __restrict__ planes, const float* __restrict__ biasT,
                            float* __restrict__ out) {
    long idx = (long)blockIdx.x * 256 + threadIdx.x;
    if (idx >= (long)MR * NN / 8) return;
    size_t base = (size_t)idx * 8;
    long r = base >> 10;
    int t = (int)(base & (NN - 1));
    float s[8] = {};
#pragma unroll
    for (int z = 0; z < 4; z++) {
        short8 v = *(const short8*)(planes + (size_t)z * MR * NN + base);
#pragma unroll
        for (int j = 0; j < 8; j++) s[j] += bu2f((unsigned short)v[j]);
    }
    const float* bT = biasT + (r >> 7) * NN + t;
    float4 o0 = {s[0] + bT[0], s[1] + bT[1], s[2] + bT[2], s[3] + bT[3]};
    float4 o1 = {s[4] + bT[4], s[5] + bT[5], s[6] + bT[6], s[7] + bT[7]};
    *(float4*)(out + base) = o0;
    *(float4*)(out + base + 4) = o1;
}

// ---------------------------------------------------------------------------
// 128^2 MFMA GEMM (L1 only): EPI1 = relu(acc+bias)*gate -> bf16, per-z expert
// ---------------------------------------------------------------------------
__device__ __forceinline__ void xcd_swizzle(int* px, int* py) {
    int gx = gridDim.x;
    int orig = blockIdx.x + gx * blockIdx.y;
    int q = (gx * gridDim.y) >> 3;
    int wg = (orig & 7) * q + (orig >> 3);
    *px = wg % gx;
    *py = wg / gx;
}

template <int EPI>
__global__ void gemm_mfma(const bf16* __restrict__ A, int lda,
                          const bf16* __restrict__ B, int ldb, size_t zBstride,
                          void* __restrict__ Cv, int ldc, size_t zCoff,
                          int N, int K, int kPerZ,
                          const int* __restrict__ se2,
                          const float* __restrict__ biasR, const float* __restrict__ biasI,
                          int zBias, const float* __restrict__ gate8) {
    __shared__ bf16 As[128 * 32];
    __shared__ bf16 Bs[128 * 32];
    int tid = threadIdx.x;
    int zz = blockIdx.z;
    int bx, by;
    xcd_swizzle(&bx, &by);
    int row0 = by * 128, col0 = bx * 128;
    const bf16* Bz = B + (size_t)zz * zBstride;

    int kS, kE;
    if (EPI == 1) { int s = se2[2 * zz], e = se2[2 * zz + 1]; kS = (2 * s) & ~31; kE = (2 * e + 31) & ~31; }
    else          { kS = zz * kPerZ; kE = min(K, kS + kPerZ); }

    f32x4 acc[4][4] = {};

    int lane = tid & 63, wid = tid >> 6;
    int wrB = (wid >> 1) << 6, wcB = (wid & 1) << 6;
    int lr = lane & 15, lk = (lane >> 4) << 3;

    int r_a = tid >> 2, c_a = (tid & 3) << 3;
    int r_b = (tid + 256) >> 2, c_b = ((tid + 256) & 3) << 3;

    for (int kt = kS; kt < kE; kt += 32) {
        gload16(A + (size_t)(row0 + r_a) * lda + kt + c_a, &As[(size_t)tid * 8]);
        gload16(A + (size_t)(row0 + r_b) * lda + kt + c_b, &As[((size_t)tid + 256) * 8]);
        gload16(Bz + (size_t)(col0 + r_a) * ldb + kt + c_a, &Bs[(size_t)tid * 8]);
        gload16(Bz + (size_t)(col0 + r_b) * ldb + kt + c_b, &Bs[((size_t)tid + 256) * 8]);
        __syncthreads();
        short8 av[4], bv[4];
#pragma unroll
        for (int m = 0; m < 4; m++)
            av[m] = *(const short8*)&As[(wrB + m * 16 + lr) * 32 + lk];
#pragma unroll
        for (int n = 0; n < 4; n++)
            bv[n] = *(const short8*)&Bs[(wcB + n * 16 + lr) * 32 + lk];
#pragma unroll
        for (int m = 0; m < 4; m++)
#pragma unroll
            for (int n = 0; n < 4; n++)
                acc[m][n] = __builtin_amdgcn_mfma_f32_16x16x32_bf16(av[m], bv[n], acc[m][n], 0, 0, 0);
        __syncthreads();
    }

    int r0 = row0 + wrB + ((lane >> 4) << 2);
    int c0i = col0 + wcB + (lane & 15);
    float g = (EPI == 1) ? gate8[(row0 >> 7) * NE + zz] : 0.0f;

#pragma unroll
    for (int m = 0; m < 4; m++)
#pragma unroll
        for (int n = 0; n < 4; n++) {
            int c = c0i + n * 16;
            if (c >= N) continue;
#pragma unroll
            for (int j = 0; j < 4; j++) {
                int r = r0 + m * 16 + j;
                float v = acc[m][n][j];
                if (EPI == 1) {
                    v += (c < HD) ? biasR[zz * zBias + c] : biasI[zz * zBias + c - HD];
                    v = fmaxf(v, 0.0f) * g;
                    ((bf16*)Cv + (size_t)zz * zCoff)[(size_t)r * ldc + c] = f2b(v);
                } else {
                    ((float*)Cv + (size_t)zz * zCoff)[(size_t)r * ldc + c] = v;
                }
            }
        }
}

// ---------------------------------------------------------------------------
// 8-phase 256x256 GEMM body — R10-proven schedule (FROZEN; best measured).
// ---------------------------------------------------------------------------
__device__ __forceinline__ void stage_half(const bf16* gbase, int ld, int kt,
                                           bf16* ldsBase, int tid) {
#pragma unroll
    for (int j = 0; j < 2; j++) {
        int r = j * 64 + (tid >> 3);
        int sc = ((tid & 7) ^ ((tid >> 3) & 7)) * 8;
        gload16(gbase + (size_t)r * ld + kt + sc, ldsBase + j * 4096 + tid * 8);
    }
}

#define MF(a, b, c) __builtin_amdgcn_mfma_f32_16x16x32_bf16(a, b, c, 0, 0, 0)
#define RD(off) (*(const short8*)(bc + (off)))
#define LOADA(dst, FM)                                                        \
    dst[0] = RD(aBase + (FM) * 1024 + cb0);                                   \
    dst[1] = RD(aBase + (FM) * 1024 + cb1);                                   \
    dst[2] = RD(aBase + (FM + 1) * 1024 + cb0);                               \
    dst[3] = RD(aBase + (FM + 1) * 1024 + cb1);
#define CLUST(FM, av)                                                         \
    __builtin_amdgcn_s_setprio(1);                                            \
    acc[FM][0] = MF(av[0], b0[0], acc[FM][0]);                                \
    acc[FM][0] = MF(av[1], b1[0], acc[FM][0]);                                \
    acc[FM][1] = MF(av[0], b0[1], acc[FM][1]);                                \
    acc[FM][1] = MF(av[1], b1[1], acc[FM][1]);                                \
    acc[FM][2] = MF(av[0], b0[2], acc[FM][2]);                                \
    acc[FM][2] = MF(av[1], b1[2], acc[FM][2]);                                \
    acc[FM][3] = MF(av[0], b0[3], acc[FM][3]);                                \
    acc[FM][3] = MF(av[1], b1[3], acc[FM][3]);                                \
    acc[FM + 1][0] = MF(av[2], b0[0], acc[FM + 1][0]);                        \
    acc[FM + 1][0] = MF(av[3], b1[0], acc[FM + 1][0]);                        \
    acc[FM + 1][1] = MF(av[2], b0[1], acc[FM + 1][1]);                        \
    acc[FM + 1][1] = MF(av[3], b1[1], acc[FM + 1][1]);                        \
    acc[FM + 1][2] = MF(av[2], b0[2], acc[FM + 1][2]);                        \
    acc[FM + 1][2] = MF(av[3], b1[2], acc[FM + 1][2]);                        \
    acc[FM + 1][3] = MF(av[2], b0[3], acc[FM + 1][3]);                        \
    acc[FM + 1][3] = MF(av[3], b1[3], acc[FM + 1][3]);                        \
    __builtin_amdgcn_s_setprio(0);
#define PBAR { __builtin_amdgcn_sched_barrier(0); __builtin_amdgcn_s_barrier(); }

__device__ __forceinline__ void gemm8p_body(
        bf16* sm, const bf16* __restrict__ A, int lda,
        const bf16* __restrict__ B, int ldb,
        bf16* __restrict__ C, int ldc,
        int row0, int col0, int kS, int nt) {
    int tid = threadIdx.x;
    const bf16* Ab = A + (size_t)row0 * lda;
    const bf16* Bb = B + (size_t)col0 * ldb;

    // prologue: stage tile 0 into buf0
    stage_half(Ab, lda, kS, sm, tid);
    stage_half(Ab + (size_t)128 * lda, lda, kS, sm + 8192, tid);
    stage_half(Bb, ldb, kS, sm + 16384, tid);
    stage_half(Bb + (size_t)128 * ldb, ldb, kS, sm + 24576, tid);

    f32x4 acc[8][4] = {};

    int l = tid & 63, w = tid >> 6;
    int wm = w >> 2, wn = w & 3;
    int lr = l & 15, lk4 = l >> 4;
    int swz = lr & 7;
    int cb0 = ((lk4) ^ swz) * 8;
    int cb1 = ((4 + lk4) ^ swz) * 8;
    int aBase = wm * 8192 + lr * 64;
    int bBase = 16384 + (wn >> 1) * 8192 + (wn & 1) * 4096 + lr * 64;

    for (int t = 0; t < nt; ++t) {
        const bf16* bc = sm + (t & 1) * 32768;
        bf16* bufN = sm + ((t & 1) ^ 1) * 32768;
        int ktn = kS + (t + 1) * 64;
        bool more = (t + 1) < nt;
        // tile boundary: stage A halves of t+1, counted vmcnt, barrier
        if (more) {
            stage_half(Ab, lda, ktn, bufN, tid);
            stage_half(Ab + (size_t)128 * lda, lda, ktn, bufN + 8192, tid);
            asm volatile("s_waitcnt vmcnt(4)" ::: "memory");
        } else {
            asm volatile("s_waitcnt vmcnt(0)" ::: "memory");
        }
        __builtin_amdgcn_s_barrier();
        __builtin_amdgcn_sched_barrier(0);
        short8 b0[4], b1[4], a0[4], a1[4], a2[4], a3[4];
#pragma unroll
        for (int n = 0; n < 4; n++) {
            b0[n] = RD(bBase + n * 1024 + cb0);
            b1[n] = RD(bBase + n * 1024 + cb1);
        }
        LOADA(a0, 0)
        LOADA(a1, 2)
        __builtin_amdgcn_sched_barrier(0);
        CLUST(0, a0)
        if (more) {                  // stage B halves of t+1 under compute
            stage_half(Bb, ldb, ktn, bufN + 16384, tid);
            stage_half(Bb + (size_t)128 * ldb, ldb, ktn, bufN + 24576, tid);
        }
        LOADA(a2, 4)
        PBAR
        CLUST(2, a1)
        LOADA(a3, 6)
        PBAR
        CLUST(4, a2)
        PBAR
        CLUST(6, a3)
        PBAR
    }

    // epilogue: bf16 store, exact dims
    int rb = row0 + wm * 128 + lk4 * 4;
    int cbase = col0 + wn * 64 + lr;
#pragma unroll
    for (int fm = 0; fm < 8; fm++)
#pragma unroll
        for (int n = 0; n < 4; n++)
#pragma unroll
            for (int j = 0; j < 4; j++)
                C[(size_t)(rb + fm * 16 + j) * ldc + cbase + n * 16] = f2b(acc[fm][n][j]);
}

// combo: blocks [0,nb0) run job0 (B2inv), [nb0,total) run job1 (DFT).
__global__ __launch_bounds__(512, 2) void gemm8p_combo(
        const bf16* A0, int lda0, const bf16* B0, int ldb0, bf16* C0, int ldc0,
        int gx0, int nt0, int nb0,
        const bf16* A1, int lda1, const bf16* B1w, int ldb1, bf16* C1, int ldc1,
        int gx1, int nt1) {
    __shared__ bf16 sm[65536];
    int id = blockIdx.x;
    bool p0 = id < nb0;
    const bf16* A = p0 ? A0 : A1; int lda = p0 ? lda0 : lda1;
    const bf16* B = p0 ? B0 : B1w; int ldb = p0 ? ldb0 : ldb1;
    bf16* C = p0 ? C0 : C1; int ldc = p0 ? ldc0 : ldc1;
    int gx = p0 ? gx0 : gx1, nt = p0 ? nt0 : nt1;
    int id2 = p0 ? id : id - nb0;
    int bx = id2 % gx, by = id2 / gx;
    gemm8p_body(sm, A, lda, B, ldb, C, ldc, by * 256, bx * 256, 0, nt);
}

// L2: 256 blocks, XCD-bijective (4x,16y,4z) mapping, z slices K.
__global__ __launch_bounds__(512, 2) void gemm8p_l2(
        const bf16* __restrict__ A, int lda, const bf16* __restrict__ B, int ldb,
        bf16* __restrict__ C, int ldc, size_t zCoff, int tilesPerZ) {
    __shared__ bf16 sm[65536];
    int id = blockIdx.x;
    int by_z = (id & 7) * 8 + (id >> 5);
    int bx = (id >> 3) & 3;
    int z = by_z >> 4;
    int by = by_z & 15;
    gemm8p_body(sm, A, lda, B, ldb, C + (size_t)z * zCoff, ldc,
                by * 256, bx * 256, z * tilesPerZ * 64, tilesPerZ);
}

// ---------------------------------------------------------------------------
extern "C" void kernel_launch(void* const* d_in, const int* in_sizes, int n_in,
                              void* d_out, int out_size, void* d_ws, size_t ws_size,
                              hipStream_t stream) {
    const float* X   = (const float*)d_in[0];
    const float* bp  = (const float*)d_in[1];
    const float* W1r = (const float*)d_in[2];
    const float* W1i = (const float*)d_in[3];
    const float* b1r = (const float*)d_in[4];
    const float* b1i = (const float*)d_in[5];
    const float* W2r = (const float*)d_in[6];
    const float* W2i = (const float*)d_in[7];
    const float* b2r = (const float*)d_in[8];
    const float* b2i = (const float*)d_in[9];
    const float* gW  = (const float*)d_in[10];
    const float* gb  = (const float*)d_in[11];
    float* out = (float*)d_out;

    const size_t SZH = (size_t)MR * HP_LD * 2;   // 136.3 MB total for Hp

    // ---- carve workspace (~267.5 MB; proven budget from R6)
    char* p = (char*)d_ws;
    auto alloc = [&](size_t bytes) -> char* {
        char* r = p; p += (bytes + 255) & ~255ULL; return r;
    };
    int*   se     = (int*)alloc(64 * 4);
    float2* sctab = (float2*)alloc(NN * sizeof(float2));
    float* magp   = (float*)alloc((size_t)BATCH * 8 * MAG_LD * 4);
    float* gate   = (float*)alloc((size_t)BATCH * NE * 4);
    float* biasCs = (float*)alloc((size_t)BATCH * BIAS_LD * 4);
    float* biasT  = (float*)alloc((size_t)BATCH * NN * 4);
    bf16*  Ffwd   = (bf16*)alloc((size_t)FF_ROWS * NN * 2);
    bf16*  Finv   = (bf16*)alloc((size_t)NN * FINV_LD * 2);
    // B1 slot (44.6 MB): B1 through L1, then L2 output planes (33.6 MB)
    char*  b1slot = alloc((size_t)NE * B1_ROWS * XINT_LD * 2);
    bf16*  B1     = (bf16*)b1slot;
    bf16*  planesB = (bf16*)b1slot;
    bf16*  B2t    = (bf16*)alloc((size_t)KCAT * FINV_LD * 2);
    bf16*  Xint   = (bf16*)alloc((size_t)MR * XINT_LD * 2);
    bf16*  B2inv  = (bf16*)alloc((size_t)NN * KCAT * 2);       // own slot (34.1 MB)
    bf16*  Hp     = (bf16*)alloc(8 * SZH);
    bf16*  Xb     = (bf16*)((char*)Hp + 8 * SZH - (size_t)MR * NN * 2);  // Hp tail

    // ---- prep (bounds+table, LDS-free bulk, LDS transpose)
    prep_kernel<<<4, 256, 0, stream>>>(bp, se, sctab);
    prep_bulk<<<(unsigned)((N_PREP + 255) / 256), 256, 0, stream>>>(
        W1r, W1i, X, se, sctab, Ffwd, Finv, B1, Xb);
    pack_B2t<<<dim3(9, 17, 8), 256, 0, stream>>>(W2r, W2i, B2t);

    // ---- combo: B2inv[1024][16640] = Finv * B2t^T (260 blocks)
    //           ∥ DFT: Xint[4096][1280] = Xb * Ffwd^T  (80 blocks)
    gemm8p_combo<<<340, 512, 0, stream>>>(
        Finv, FINV_LD, B2t, FINV_LD, B2inv, KCAT, 65, 17, 260,
        Xb, NN, Ffwd, NN, Xint, XINT_LD, 5, 16);

    // ---- gate path (mag partials -> gate+biasCs -> biasT, R10 form)
    mag_kernel<<<dim3(BATCH, 8), 256, 0, stream>>>(Xint, magp);
    gate_bias_kernel<<<BATCH, 256, 0, stream>>>(magp, gW, gb, b2r, b2i, gate, biasCs);
    biasT_kernel<<<dim3(4, BATCH), 256, 0, stream>>>(biasCs, Ffwd, biasT);

    // ---- L1 (all 8 experts, gate folded): Hp[4096][16640]  (B1 still intact)
    gemm_mfma<1><<<dim3(17, 32, 8), 256, 0, stream>>>(
        Xint, XINT_LD, B1, XINT_LD, (size_t)B1_ROWS * XINT_LD,
        Hp, KCAT, HP_LD, 2 * HD, 0, 0,
        se, b1r, b1i, HD, gate);

    // ---- L2+iDFT fused: plane_z = Hp * B2inv^T over z's K-slice
    //      (planes live in B1's slot — B1 dead after L1)
    gemm8p_l2<<<256, 512, 0, stream>>>(
        Hp, KCAT, B2inv, KCAT, planesB, NN, (size_t)MR * NN, 65);

    // ---- reduce 4 planes + biasT -> out
    reduce_out4<<<(unsigned)(((size_t)MR * NN / 8 + 255) / 256), 256, 0, stream>>>(
        planesB, biasT, out);
}